// Round 10
// baseline (518.000 us; speedup 1.0000x reference)
//
#include <hip/hip_runtime.h>

#define EMBED_DIM 64
#define NBLK_A 256            // blocks in bucket count/scatter passes
#define BUCKET_SHIFT 9        // 512 rows per bucket
#define BUCKET_ROWS 512
#define MAX_NBUCK 640
#define SCAN2_CHUNK 2048      // 256 threads x 8
#define COL_BITS 19           // col < 2^19; meta = (localrow << 19) | col

typedef float fx4 __attribute__((ext_vector_type(4)));
typedef int   ix4 __attribute__((ext_vector_type(4)));
typedef float fv4 __attribute__((ext_vector_type(4)));
typedef _Float16 h8v __attribute__((ext_vector_type(8)));

// ---------- convert concat(user_emb, item_emb) fp32 -> fp16 ----------
__global__ void convert_x_kernel(const float* __restrict__ ue, const float* __restrict__ ie,
                                 _Float16* __restrict__ xh, int nu_elems, int total) {
    int i = blockIdx.x * blockDim.x + threadIdx.x;   // index in units of 8 elems
    int stride = gridDim.x * blockDim.x;
    int n8 = total >> 3;
    int nu8 = nu_elems >> 3;
    for (; i < n8; i += stride) {
        const float4* src = (i < nu8) ? (const float4*)(ue) + 2 * i
                                      : (const float4*)(ie) + 2 * (i - nu8);
        float4 lo = src[0];
        float4 hi = src[1];
        h8v o;
        o[0] = (_Float16)lo.x; o[1] = (_Float16)lo.y;
        o[2] = (_Float16)lo.z; o[3] = (_Float16)lo.w;
        o[4] = (_Float16)hi.x; o[5] = (_Float16)hi.y;
        o[6] = (_Float16)hi.z; o[7] = (_Float16)hi.w;
        reinterpret_cast<h8v*>(xh)[i] = o;
    }
}

// ---------- pass A1: per-block bucket histogram (LDS), bucket-major dump ----------
__global__ __launch_bounds__(256) void bucket_count_kernel(
    const int* __restrict__ rows, int* __restrict__ blockCounts,
    int nnz, int nbuck, int chunk) {
    __shared__ int hist[MAX_NBUCK];
    int t = threadIdx.x, blk = blockIdx.x;
    for (int i = t; i < nbuck; i += 256) hist[i] = 0;
    __syncthreads();
    int e0 = blk * chunk;
    int e1 = min(e0 + chunk, nnz);
    for (int e = e0 + t * 4; e < e1; e += 1024) {
        ix4 r4 = __builtin_nontemporal_load(reinterpret_cast<const ix4*>(rows + e));
        atomicAdd(&hist[r4.x >> BUCKET_SHIFT], 1);
        atomicAdd(&hist[r4.y >> BUCKET_SHIFT], 1);
        atomicAdd(&hist[r4.z >> BUCKET_SHIFT], 1);
        atomicAdd(&hist[r4.w >> BUCKET_SHIFT], 1);
    }
    __syncthreads();
    for (int u = t; u < nbuck; u += 256)
        blockCounts[u * NBLK_A + blk] = hist[u];
}

// ---------- scan phase 1 (chunk 2048): per-block sums ----------
__global__ void scan8_phase1(const int* __restrict__ in, int* __restrict__ bsum, int n) {
    __shared__ int wsum[4];
    int t = threadIdx.x, b = blockIdx.x;
    int i0 = b * SCAN2_CHUNK + t * 8;
    int s = 0;
    #pragma unroll
    for (int k = 0; k < 8; ++k) { int i = i0 + k; if (i < n) s += in[i]; }
    #pragma unroll
    for (int off = 1; off < 64; off <<= 1) s += __shfl_xor(s, off);
    if ((t & 63) == 0) wsum[t >> 6] = s;
    __syncthreads();
    if (t == 0) bsum[b] = wsum[0] + wsum[1] + wsum[2] + wsum[3];
}

// ---------- scan phase 2: single-block scan of block sums (nb <= 512) ----------
__global__ void scan_phase2(const int* __restrict__ bsum, int* __restrict__ boff, int nb) {
    __shared__ int lds[512];
    int t = threadIdx.x;
    lds[t] = (t < nb) ? bsum[t] : 0;
    __syncthreads();
    for (int off = 1; off < 512; off <<= 1) {
        int v = (t >= off) ? lds[t - off] : 0;
        __syncthreads();
        lds[t] += v;
        __syncthreads();
    }
    if (t < nb) boff[t] = (t == 0) ? 0 : lds[t - 1];
}

// ---------- scan phase 3 (chunk 2048): write exclusive prefix ----------
__global__ void scan8_phase3(const int* __restrict__ in, const int* __restrict__ boff,
                             int* __restrict__ out, int n) {
    __shared__ int wexcl[4];
    int t = threadIdx.x, b = blockIdx.x;
    int lane = t & 63, w = t >> 6;
    int i0 = b * SCAN2_CHUNK + t * 8;
    int c[8];
    int s = 0;
    #pragma unroll
    for (int k = 0; k < 8; ++k) { int i = i0 + k; c[k] = (i < n) ? in[i] : 0; s += c[k]; }
    int incl = s;
    #pragma unroll
    for (int off = 1; off < 64; off <<= 1) {
        int u = __shfl_up(incl, off);
        if (lane >= off) incl += u;
    }
    if (lane == 63) wexcl[w] = incl;
    __syncthreads();
    int wbase = 0;
    for (int ww = 0; ww < w; ++ww) wbase += wexcl[ww];
    int run = incl - s + wbase + boff[b];
    #pragma unroll
    for (int k = 0; k < 8; ++k) {
        int i = i0 + k;
        if (i < n) { out[i] = run; run += c[k]; }
    }
}

// ---------- pass A3: scatter edges into bucket-partitioned staging (LDS cursors) ----------
__global__ __launch_bounds__(256) void bucket_scatter_kernel(
    const int* __restrict__ rows, const int* __restrict__ cols,
    const float* __restrict__ vals, const int* __restrict__ scanOut,
    int2* __restrict__ smeta, int nnz, int nbuck, int chunk) {
    __shared__ int cur[MAX_NBUCK];
    int t = threadIdx.x, blk = blockIdx.x;
    for (int u = t; u < nbuck; u += 256) cur[u] = scanOut[u * NBLK_A + blk];
    __syncthreads();
    int e0 = blk * chunk;
    int e1 = min(e0 + chunk, nnz);
    for (int e = e0 + t * 4; e < e1; e += 1024) {
        ix4 r4 = __builtin_nontemporal_load(reinterpret_cast<const ix4*>(rows + e));
        ix4 c4 = __builtin_nontemporal_load(reinterpret_cast<const ix4*>(cols + e));
        fv4 v4 = __builtin_nontemporal_load(reinterpret_cast<const fv4*>(vals + e));
        int p0 = atomicAdd(&cur[r4.x >> BUCKET_SHIFT], 1);
        smeta[p0] = make_int2(((r4.x & (BUCKET_ROWS - 1)) << COL_BITS) | c4.x, __float_as_int(v4.x));
        int p1 = atomicAdd(&cur[r4.y >> BUCKET_SHIFT], 1);
        smeta[p1] = make_int2(((r4.y & (BUCKET_ROWS - 1)) << COL_BITS) | c4.y, __float_as_int(v4.y));
        int p2 = atomicAdd(&cur[r4.z >> BUCKET_SHIFT], 1);
        smeta[p2] = make_int2(((r4.z & (BUCKET_ROWS - 1)) << COL_BITS) | c4.z, __float_as_int(v4.z));
        int p3 = atomicAdd(&cur[r4.w >> BUCKET_SHIFT], 1);
        smeta[p3] = make_int2(((r4.w & (BUCKET_ROWS - 1)) << COL_BITS) | c4.w, __float_as_int(v4.w));
    }
}

// ---------- pass B: per-bucket counting sort -> row_ptr + perm ----------
__global__ __launch_bounds__(256) void bucket_build_kernel(
    const int2* __restrict__ smeta, const int* __restrict__ scanOut,
    int2* __restrict__ perm, int* __restrict__ row_ptr,
    int nnz, int n_nodes, int nbuck) {
    __shared__ int hist[BUCKET_ROWS], excl[BUCKET_ROWS], cur[BUCKET_ROWS];
    __shared__ int wex[4];
    int t = threadIdx.x, b = blockIdx.x;
    int lane = t & 63, w = t >> 6;
    int ebeg = scanOut[b * NBLK_A];
    int eend = (b + 1 < nbuck) ? scanOut[(b + 1) * NBLK_A] : nnz;
    hist[t] = 0; hist[t + 256] = 0;
    __syncthreads();
    for (int e = ebeg + t; e < eend; e += 256)
        atomicAdd(&hist[smeta[e].x >> COL_BITS], 1);
    __syncthreads();
    int a = hist[2 * t], bcnt = hist[2 * t + 1];
    int s = a + bcnt;
    int incl = s;
    #pragma unroll
    for (int off = 1; off < 64; off <<= 1) {
        int u = __shfl_up(incl, off);
        if (lane >= off) incl += u;
    }
    if (lane == 63) wex[w] = incl;
    __syncthreads();
    int wbase = 0;
    for (int ww = 0; ww < w; ++ww) wbase += wex[ww];
    int es = wbase + incl - s;
    excl[2 * t] = es;
    excl[2 * t + 1] = es + a;
    cur[2 * t] = es;
    cur[2 * t + 1] = es + a;
    __syncthreads();
    int base_row = b << BUCKET_SHIFT;
    for (int r = t; r < BUCKET_ROWS; r += 256) {
        int gr = base_row + r;
        if (gr < n_nodes) row_ptr[gr] = ebeg + excl[r];
    }
    if (b == 0 && t == 0) row_ptr[n_nodes] = nnz;
    for (int e = ebeg + t; e < eend; e += 256) {
        int2 m = smeta[e];
        int l = m.x >> COL_BITS;
        int p = atomicAdd(&cur[l], 1);
        perm[ebeg + p] = make_int2(m.x & ((1 << COL_BITS) - 1), m.y);
    }
}

// ---------- batch accumulator init (float4, from fp32 embeddings) ----------
__global__ void init_bacc_kernel(const float* __restrict__ ue, const float* __restrict__ ie,
                                 const int* __restrict__ uids, const int* __restrict__ iids,
                                 float* __restrict__ uacc, float* __restrict__ iacc, int batch) {
    int t = blockIdx.x * blockDim.x + threadIdx.x;
    if (t >= batch * 16) return;
    int b = t >> 4;
    int q = t & 15;
    const float4* ue4 = (const float4*)ue;
    const float4* ie4 = (const float4*)ie;
    ((float4*)uacc)[t] = ue4[(long)uids[b] * 16 + q];
    ((float4*)iacc)[t] = ie4[(long)iids[b] * 16 + q];
}

// ---------- fp16 CSR gather SpMM: one wave per row, 8 edge-slots x 8 dim-lanes ----------
// 24 edges per iteration (3 independent groups); perm loaded nontemporally to
// keep the x working set resident in L2. fp32 accumulate, fp16 store.
__global__ __launch_bounds__(256) void spmm_csr_h_kernel(
    const int* __restrict__ row_ptr, const int2* __restrict__ perm,
    const _Float16* __restrict__ x, _Float16* __restrict__ y, int n_nodes) {
    int lane = threadIdx.x & 63;
    int row = (blockIdx.x * blockDim.x + threadIdx.x) >> 6;
    if (row >= n_nodes) return;
    int start = row_ptr[row];
    int end   = row_ptr[row + 1];
    int sub  = lane >> 3;    // edge slot 0..7
    int dimq = lane & 7;     // half8 index within the 64-dim row
    const h8v* x8 = reinterpret_cast<const h8v*>(x);
    float acc0[8], acc1[8], acc2[8];
    #pragma unroll
    for (int k = 0; k < 8; ++k) { acc0[k] = 0.f; acc1[k] = 0.f; acc2[k] = 0.f; }
    for (int base = start; base < end; base += 24) {
        int e0 = base + sub;
        int e1 = e0 + 8;
        int e2 = e0 + 16;
        // clamp to valid range, then mask col/val for out-of-row slots
        int ee0 = max(min(e0, end - 1), 0);
        int ee1 = max(min(e1, end - 1), 0);
        int ee2 = max(min(e2, end - 1), 0);
        long long pv0 = __builtin_nontemporal_load((const long long*)(perm + ee0));
        long long pv1 = __builtin_nontemporal_load((const long long*)(perm + ee1));
        long long pv2 = __builtin_nontemporal_load((const long long*)(perm + ee2));
        int   c0 = (e0 < end) ? (int)pv0 : 0;   // col 0 = hot line, val forced 0
        int   c1 = (e1 < end) ? (int)pv1 : 0;
        int   c2 = (e2 < end) ? (int)pv2 : 0;
        float v0 = (e0 < end) ? __int_as_float((int)(pv0 >> 32)) : 0.f;
        float v1 = (e1 < end) ? __int_as_float((int)(pv1 >> 32)) : 0.f;
        float v2 = (e2 < end) ? __int_as_float((int)(pv2 >> 32)) : 0.f;
        h8v xv0 = x8[(long)c0 * 8 + dimq];
        h8v xv1 = x8[(long)c1 * 8 + dimq];
        h8v xv2 = x8[(long)c2 * 8 + dimq];
        #pragma unroll
        for (int k = 0; k < 8; ++k) acc0[k] = fmaf(v0, (float)xv0[k], acc0[k]);
        #pragma unroll
        for (int k = 0; k < 8; ++k) acc1[k] = fmaf(v1, (float)xv1[k], acc1[k]);
        #pragma unroll
        for (int k = 0; k < 8; ++k) acc2[k] = fmaf(v2, (float)xv2[k], acc2[k]);
    }
    float accf[8];
    #pragma unroll
    for (int k = 0; k < 8; ++k) accf[k] = acc0[k] + acc1[k] + acc2[k];
    #pragma unroll
    for (int off = 8; off < 64; off <<= 1) {
        #pragma unroll
        for (int k = 0; k < 8; ++k) accf[k] += __shfl_xor(accf[k], off);
    }
    if (sub == 0) {
        h8v o;
        #pragma unroll
        for (int k = 0; k < 8; ++k) o[k] = (_Float16)accf[k];
        reinterpret_cast<h8v*>(y)[(long)row * 8 + dimq] = o;
    }
}

// ---------- layer-3 batch-restricted SpMM (fp16 x), accumulate into fp32 acc ----------
__global__ __launch_bounds__(256) void spmm_batch_h_kernel(
    const int* __restrict__ row_ptr, const int2* __restrict__ perm,
    const _Float16* __restrict__ x,
    const int* __restrict__ uids, const int* __restrict__ iids,
    float* __restrict__ uacc, float* __restrict__ iacc,
    int batch, int num_users) {
    int lane = threadIdx.x & 63;
    int w = (blockIdx.x * blockDim.x + threadIdx.x) >> 6;
    if (w >= 2 * batch) return;
    int row;
    float* target;
    if (w < batch) { row = uids[w];                     target = uacc + (long)w * EMBED_DIM; }
    else           { row = num_users + iids[w - batch]; target = iacc + (long)(w - batch) * EMBED_DIM; }
    int start = row_ptr[row];
    int end   = row_ptr[row + 1];
    int sub  = lane >> 3;
    int dimq = lane & 7;
    const h8v* x8 = reinterpret_cast<const h8v*>(x);
    float acc0[8], acc1[8], acc2[8];
    #pragma unroll
    for (int k = 0; k < 8; ++k) { acc0[k] = 0.f; acc1[k] = 0.f; acc2[k] = 0.f; }
    for (int base = start; base < end; base += 24) {
        int e0 = base + sub;
        int e1 = e0 + 8;
        int e2 = e0 + 16;
        int ee0 = max(min(e0, end - 1), 0);
        int ee1 = max(min(e1, end - 1), 0);
        int ee2 = max(min(e2, end - 1), 0);
        long long pv0 = __builtin_nontemporal_load((const long long*)(perm + ee0));
        long long pv1 = __builtin_nontemporal_load((const long long*)(perm + ee1));
        long long pv2 = __builtin_nontemporal_load((const long long*)(perm + ee2));
        int   c0 = (e0 < end) ? (int)pv0 : 0;
        int   c1 = (e1 < end) ? (int)pv1 : 0;
        int   c2 = (e2 < end) ? (int)pv2 : 0;
        float v0 = (e0 < end) ? __int_as_float((int)(pv0 >> 32)) : 0.f;
        float v1 = (e1 < end) ? __int_as_float((int)(pv1 >> 32)) : 0.f;
        float v2 = (e2 < end) ? __int_as_float((int)(pv2 >> 32)) : 0.f;
        h8v xv0 = x8[(long)c0 * 8 + dimq];
        h8v xv1 = x8[(long)c1 * 8 + dimq];
        h8v xv2 = x8[(long)c2 * 8 + dimq];
        #pragma unroll
        for (int k = 0; k < 8; ++k) acc0[k] = fmaf(v0, (float)xv0[k], acc0[k]);
        #pragma unroll
        for (int k = 0; k < 8; ++k) acc1[k] = fmaf(v1, (float)xv1[k], acc1[k]);
        #pragma unroll
        for (int k = 0; k < 8; ++k) acc2[k] = fmaf(v2, (float)xv2[k], acc2[k]);
    }
    float accf[8];
    #pragma unroll
    for (int k = 0; k < 8; ++k) accf[k] = acc0[k] + acc1[k] + acc2[k];
    #pragma unroll
    for (int off = 8; off < 64; off <<= 1) {
        #pragma unroll
        for (int k = 0; k < 8; ++k) accf[k] += __shfl_xor(accf[k], off);
    }
    if (sub == 0) {
        fx4* t4 = reinterpret_cast<fx4*>(target) + dimq * 2;
        fx4 lo = t4[0], hi = t4[1];
        lo.x += accf[0]; lo.y += accf[1]; lo.z += accf[2]; lo.w += accf[3];
        hi.x += accf[4]; hi.y += accf[5]; hi.z += accf[6]; hi.w += accf[7];
        t4[0] = lo; t4[1] = hi;
    }
}

// ---------- per-layer batch accumulate: fp16 y -> fp32 acc ----------
__global__ void bacc_add_h_kernel(const _Float16* __restrict__ y,
                                  const int* __restrict__ uids, const int* __restrict__ iids,
                                  float* __restrict__ uacc, float* __restrict__ iacc,
                                  int batch, int num_users) {
    int t = blockIdx.x * blockDim.x + threadIdx.x;
    if (t >= batch * 8) return;
    int b = t >> 3;
    int q = t & 7;
    const h8v* y8 = (const h8v*)y;
    h8v u = y8[(long)uids[b] * 8 + q];
    h8v v = y8[((long)num_users + iids[b]) * 8 + q];
    float4* ua = (float4*)uacc + (long)b * 16 + q * 2;
    float4* ia = (float4*)iacc + (long)b * 16 + q * 2;
    float4 a0 = ua[0], a1 = ua[1];
    a0.x += (float)u[0]; a0.y += (float)u[1]; a0.z += (float)u[2]; a0.w += (float)u[3];
    a1.x += (float)u[4]; a1.y += (float)u[5]; a1.z += (float)u[6]; a1.w += (float)u[7];
    ua[0] = a0; ua[1] = a1;
    float4 c0 = ia[0], c1 = ia[1];
    c0.x += (float)v[0]; c0.y += (float)v[1]; c0.z += (float)v[2]; c0.w += (float)v[3];
    c1.x += (float)v[4]; c1.y += (float)v[5]; c1.z += (float)v[6]; c1.w += (float)v[7];
    ia[0] = c0; ia[1] = c1;
}

// ---------- scoring ----------
__global__ void score_kernel(const float* __restrict__ uacc, const float* __restrict__ iacc,
                             float* __restrict__ out, int batch) {
    int lane = threadIdx.x & 63;
    int w = (blockIdx.x * blockDim.x + threadIdx.x) >> 6;
    if (w >= batch) return;
    float p = uacc[(long)w * EMBED_DIM + lane] * iacc[(long)w * EMBED_DIM + lane];
    #pragma unroll
    for (int off = 32; off > 0; off >>= 1) p += __shfl_down(p, off);
    if (lane == 0) out[w] = p * (1.0f / 16.0f);  // (acc/4)·(acc/4)
}

extern "C" void kernel_launch(void* const* d_in, const int* in_sizes, int n_in,
                              void* d_out, int out_size, void* d_ws, size_t ws_size,
                              hipStream_t stream) {
    const float* user_emb = (const float*)d_in[0];
    const float* item_emb = (const float*)d_in[1];
    const int*   adj_rows = (const int*)d_in[2];
    const int*   adj_cols = (const int*)d_in[3];
    const float* adj_vals = (const float*)d_in[4];
    const int*   user_ids = (const int*)d_in[5];
    const int*   item_ids = (const int*)d_in[6];
    float* out = (float*)d_out;

    const int num_users = in_sizes[0] / EMBED_DIM;   // 200000
    const int num_items = in_sizes[1] / EMBED_DIM;   // 100000
    const int n_nodes   = num_users + num_items;     // 300000
    const int nnz       = in_sizes[2];               // 6000000
    const int batch     = in_sizes[5];               // 16384

    const long node_elems = (long)n_nodes * EMBED_DIM;    // 19.2M elems
    const long bacc_elems = (long)batch * EMBED_DIM;      // 1.05M floats

    const int nbuck = (n_nodes + BUCKET_ROWS - 1) >> BUCKET_SHIFT;   // 586
    const int nscan = nbuck * NBLK_A;                                // 150016
    const int nscan_blocks = (nscan + SCAN2_CHUNK - 1) / SCAN2_CHUNK; // 74

    // ---- workspace layout ----
    char* wp = (char*)d_ws;
    _Float16* xh   = (_Float16*)wp;      wp += node_elems * sizeof(_Float16);
    _Float16* bufA = (_Float16*)wp;      wp += node_elems * sizeof(_Float16);
    _Float16* bufB = (_Float16*)wp;      wp += node_elems * sizeof(_Float16);
    float* uacc = (float*)wp;            wp += bacc_elems * sizeof(float);
    float* iacc = (float*)wp;            wp += bacc_elems * sizeof(float);
    int*   row_ptr = (int*)wp;           wp += (size_t)(n_nodes + 4) * sizeof(int);
    int*   bsum    = (int*)wp;           wp += 512 * sizeof(int);
    int*   boff    = (int*)wp;           wp += 512 * sizeof(int);
    int*   blockCounts = (int*)wp;       wp += (size_t)nscan * sizeof(int);
    int*   scanOut     = (int*)wp;       wp += (size_t)nscan * sizeof(int);
    wp = (char*)(((uintptr_t)wp + 15) & ~(uintptr_t)15);
    int2*  perm    = (int2*)wp;          wp += (size_t)nnz * sizeof(int2);

    // smeta staging (48 MB) overlays bufA+bufB (76.8 MB contiguous): both are
    // first written by spmm layers, which run after bucket_build consumes smeta.
    int2* smeta = (int2*)bufA;

    const int chunkA = (((nnz + NBLK_A - 1) / NBLK_A) + 1023) & ~1023;   // 24576

    // ---- radix CSR build (no device atomics) ----
    bucket_count_kernel<<<NBLK_A, 256, 0, stream>>>(adj_rows, blockCounts, nnz, nbuck, chunkA);
    scan8_phase1<<<nscan_blocks, 256, 0, stream>>>(blockCounts, bsum, nscan);
    scan_phase2<<<1, 512, 0, stream>>>(bsum, boff, nscan_blocks);
    scan8_phase3<<<nscan_blocks, 256, 0, stream>>>(blockCounts, boff, scanOut, nscan);
    bucket_scatter_kernel<<<NBLK_A, 256, 0, stream>>>(adj_rows, adj_cols, adj_vals,
                                                      scanOut, smeta, nnz, nbuck, chunkA);
    bucket_build_kernel<<<nbuck, 256, 0, stream>>>(smeta, scanOut, perm,
                                                   row_ptr, nnz, n_nodes, nbuck);

    // ---- convert x0 to fp16 ----
    convert_x_kernel<<<2048, 256, 0, stream>>>(user_emb, item_emb, xh,
                                               num_users * EMBED_DIM, (int)node_elems);

    // ---- batch accumulator init (layer-0 term, fp32) ----
    {
        int blocks = (batch * 16 + 255) / 256;
        init_bacc_kernel<<<blocks, 256, 0, stream>>>(user_emb, item_emb, user_ids, item_ids,
                                                     uacc, iacc, batch);
    }

    const int spmm_blocks = ((n_nodes * 64) + 255) / 256;   // one wave per row
    const int bblocks = (batch * 8 + 255) / 256;

    // ---- layer 1: xh -> bufA ----
    spmm_csr_h_kernel<<<spmm_blocks, 256, 0, stream>>>(row_ptr, perm, xh, bufA, n_nodes);
    bacc_add_h_kernel<<<bblocks, 256, 0, stream>>>(bufA, user_ids, item_ids,
                                                   uacc, iacc, batch, num_users);

    // ---- layer 2: bufA -> bufB ----
    spmm_csr_h_kernel<<<spmm_blocks, 256, 0, stream>>>(row_ptr, perm, bufA, bufB, n_nodes);
    bacc_add_h_kernel<<<bblocks, 256, 0, stream>>>(bufB, user_ids, item_ids,
                                                   uacc, iacc, batch, num_users);

    // ---- layer 3 (batch-restricted): bufB -> uacc/iacc directly ----
    {
        int waves = 2 * batch;                        // 32768 waves
        int blocks = (waves * 64 + 255) / 256;        // 8192 blocks
        spmm_batch_h_kernel<<<blocks, 256, 0, stream>>>(row_ptr, perm, bufB,
                                                        user_ids, item_ids,
                                                        uacc, iacc, batch, num_users);
    }

    // ---- score ----
    {
        int blocks = (batch * 64 + 255) / 256;
        score_kernel<<<blocks, 256, 0, stream>>>(uacc, iacc, out, batch);
    }
}

// Round 11
// 497.434 us; speedup vs baseline: 1.0413x; 1.0413x over previous
//
#include <hip/hip_runtime.h>

#define EMBED_DIM 64
#define NBLK_A 256            // blocks in bucket count/scatter passes
#define BUCKET_SHIFT 9        // 512 rows per bucket
#define BUCKET_ROWS 512
#define MAX_NBUCK 640
#define SCAN2_CHUNK 2048      // 256 threads x 8
#define COL_BITS 19           // col < 2^19; meta = (localrow << 19) | col
#define STAGE_CAP 15360       // LDS staging capacity (120 KB); bucket avg 10.2K, +47 sigma

typedef float fx4 __attribute__((ext_vector_type(4)));
typedef int   ix4 __attribute__((ext_vector_type(4)));
typedef float fv4 __attribute__((ext_vector_type(4)));
typedef _Float16 h8v __attribute__((ext_vector_type(8)));

// ---------- convert concat(user_emb, item_emb) fp32 -> fp16 ----------
__global__ void convert_x_kernel(const float* __restrict__ ue, const float* __restrict__ ie,
                                 _Float16* __restrict__ xh, int nu_elems, int total) {
    int i = blockIdx.x * blockDim.x + threadIdx.x;   // index in units of 8 elems
    int stride = gridDim.x * blockDim.x;
    int n8 = total >> 3;
    int nu8 = nu_elems >> 3;
    for (; i < n8; i += stride) {
        const float4* src = (i < nu8) ? (const float4*)(ue) + 2 * i
                                      : (const float4*)(ie) + 2 * (i - nu8);
        float4 lo = src[0];
        float4 hi = src[1];
        h8v o;
        o[0] = (_Float16)lo.x; o[1] = (_Float16)lo.y;
        o[2] = (_Float16)lo.z; o[3] = (_Float16)lo.w;
        o[4] = (_Float16)hi.x; o[5] = (_Float16)hi.y;
        o[6] = (_Float16)hi.z; o[7] = (_Float16)hi.w;
        reinterpret_cast<h8v*>(xh)[i] = o;
    }
}

// ---------- pass A1: per-block bucket histogram (LDS), bucket-major dump ----------
__global__ __launch_bounds__(256) void bucket_count_kernel(
    const int* __restrict__ rows, int* __restrict__ blockCounts,
    int nnz, int nbuck, int chunk) {
    __shared__ int hist[MAX_NBUCK];
    int t = threadIdx.x, blk = blockIdx.x;
    for (int i = t; i < nbuck; i += 256) hist[i] = 0;
    __syncthreads();
    int e0 = blk * chunk;
    int e1 = min(e0 + chunk, nnz);
    for (int e = e0 + t * 4; e < e1; e += 1024) {
        ix4 r4 = __builtin_nontemporal_load(reinterpret_cast<const ix4*>(rows + e));
        atomicAdd(&hist[r4.x >> BUCKET_SHIFT], 1);
        atomicAdd(&hist[r4.y >> BUCKET_SHIFT], 1);
        atomicAdd(&hist[r4.z >> BUCKET_SHIFT], 1);
        atomicAdd(&hist[r4.w >> BUCKET_SHIFT], 1);
    }
    __syncthreads();
    for (int u = t; u < nbuck; u += 256)
        blockCounts[u * NBLK_A + blk] = hist[u];
}

// ---------- scan phase 1 (chunk 2048): per-block sums ----------
__global__ void scan8_phase1(const int* __restrict__ in, int* __restrict__ bsum, int n) {
    __shared__ int wsum[4];
    int t = threadIdx.x, b = blockIdx.x;
    int i0 = b * SCAN2_CHUNK + t * 8;
    int s = 0;
    #pragma unroll
    for (int k = 0; k < 8; ++k) { int i = i0 + k; if (i < n) s += in[i]; }
    #pragma unroll
    for (int off = 1; off < 64; off <<= 1) s += __shfl_xor(s, off);
    if ((t & 63) == 0) wsum[t >> 6] = s;
    __syncthreads();
    if (t == 0) bsum[b] = wsum[0] + wsum[1] + wsum[2] + wsum[3];
}

// ---------- scan phase 2: single-block scan of block sums (nb <= 512) ----------
__global__ void scan_phase2(const int* __restrict__ bsum, int* __restrict__ boff, int nb) {
    __shared__ int lds[512];
    int t = threadIdx.x;
    lds[t] = (t < nb) ? bsum[t] : 0;
    __syncthreads();
    for (int off = 1; off < 512; off <<= 1) {
        int v = (t >= off) ? lds[t - off] : 0;
        __syncthreads();
        lds[t] += v;
        __syncthreads();
    }
    if (t < nb) boff[t] = (t == 0) ? 0 : lds[t - 1];
}

// ---------- scan phase 3 (chunk 2048): write exclusive prefix ----------
__global__ void scan8_phase3(const int* __restrict__ in, const int* __restrict__ boff,
                             int* __restrict__ out, int n) {
    __shared__ int wexcl[4];
    int t = threadIdx.x, b = blockIdx.x;
    int lane = t & 63, w = t >> 6;
    int i0 = b * SCAN2_CHUNK + t * 8;
    int c[8];
    int s = 0;
    #pragma unroll
    for (int k = 0; k < 8; ++k) { int i = i0 + k; c[k] = (i < n) ? in[i] : 0; s += c[k]; }
    int incl = s;
    #pragma unroll
    for (int off = 1; off < 64; off <<= 1) {
        int u = __shfl_up(incl, off);
        if (lane >= off) incl += u;
    }
    if (lane == 63) wexcl[w] = incl;
    __syncthreads();
    int wbase = 0;
    for (int ww = 0; ww < w; ++ww) wbase += wexcl[ww];
    int run = incl - s + wbase + boff[b];
    #pragma unroll
    for (int k = 0; k < 8; ++k) {
        int i = i0 + k;
        if (i < n) { out[i] = run; run += c[k]; }
    }
}

// ---------- pass A3: scatter edges into bucket-partitioned staging (LDS cursors) ----------
__global__ __launch_bounds__(256) void bucket_scatter_kernel(
    const int* __restrict__ rows, const int* __restrict__ cols,
    const float* __restrict__ vals, const int* __restrict__ scanOut,
    int2* __restrict__ smeta, int nnz, int nbuck, int chunk) {
    __shared__ int cur[MAX_NBUCK];
    int t = threadIdx.x, blk = blockIdx.x;
    for (int u = t; u < nbuck; u += 256) cur[u] = scanOut[u * NBLK_A + blk];
    __syncthreads();
    int e0 = blk * chunk;
    int e1 = min(e0 + chunk, nnz);
    for (int e = e0 + t * 4; e < e1; e += 1024) {
        ix4 r4 = __builtin_nontemporal_load(reinterpret_cast<const ix4*>(rows + e));
        ix4 c4 = __builtin_nontemporal_load(reinterpret_cast<const ix4*>(cols + e));
        fv4 v4 = __builtin_nontemporal_load(reinterpret_cast<const fv4*>(vals + e));
        int p0 = atomicAdd(&cur[r4.x >> BUCKET_SHIFT], 1);
        smeta[p0] = make_int2(((r4.x & (BUCKET_ROWS - 1)) << COL_BITS) | c4.x, __float_as_int(v4.x));
        int p1 = atomicAdd(&cur[r4.y >> BUCKET_SHIFT], 1);
        smeta[p1] = make_int2(((r4.y & (BUCKET_ROWS - 1)) << COL_BITS) | c4.y, __float_as_int(v4.y));
        int p2 = atomicAdd(&cur[r4.z >> BUCKET_SHIFT], 1);
        smeta[p2] = make_int2(((r4.z & (BUCKET_ROWS - 1)) << COL_BITS) | c4.z, __float_as_int(v4.z));
        int p3 = atomicAdd(&cur[r4.w >> BUCKET_SHIFT], 1);
        smeta[p3] = make_int2(((r4.w & (BUCKET_ROWS - 1)) << COL_BITS) | c4.w, __float_as_int(v4.w));
    }
}

// ---------- pass B: per-bucket counting sort -> row_ptr + perm ----------
// Scattered writes land in a 120 KB LDS stage; perm is then written with
// fully-coalesced 8B stores. Fallback to direct scatter if a bucket overflows.
__global__ __launch_bounds__(256) void bucket_build_kernel(
    const int2* __restrict__ smeta, const int* __restrict__ scanOut,
    int2* __restrict__ perm, int* __restrict__ row_ptr,
    int nnz, int n_nodes, int nbuck) {
    __shared__ int hist[BUCKET_ROWS], excl[BUCKET_ROWS], cur[BUCKET_ROWS];
    __shared__ int wex[4];
    __shared__ int2 stage[STAGE_CAP];
    int t = threadIdx.x, b = blockIdx.x;
    int lane = t & 63, w = t >> 6;
    int ebeg = scanOut[b * NBLK_A];
    int eend = (b + 1 < nbuck) ? scanOut[(b + 1) * NBLK_A] : nnz;
    hist[t] = 0; hist[t + 256] = 0;
    __syncthreads();
    for (int e = ebeg + t; e < eend; e += 256)
        atomicAdd(&hist[smeta[e].x >> COL_BITS], 1);
    __syncthreads();
    int a = hist[2 * t], bcnt = hist[2 * t + 1];
    int s = a + bcnt;
    int incl = s;
    #pragma unroll
    for (int off = 1; off < 64; off <<= 1) {
        int u = __shfl_up(incl, off);
        if (lane >= off) incl += u;
    }
    if (lane == 63) wex[w] = incl;
    __syncthreads();
    int wbase = 0;
    for (int ww = 0; ww < w; ++ww) wbase += wex[ww];
    int es = wbase + incl - s;
    excl[2 * t] = es;
    excl[2 * t + 1] = es + a;
    cur[2 * t] = es;
    cur[2 * t + 1] = es + a;
    __syncthreads();
    int base_row = b << BUCKET_SHIFT;
    for (int r = t; r < BUCKET_ROWS; r += 256) {
        int gr = base_row + r;
        if (gr < n_nodes) row_ptr[gr] = ebeg + excl[r];
    }
    if (b == 0 && t == 0) row_ptr[n_nodes] = nnz;
    int nbe = eend - ebeg;
    if (nbe <= STAGE_CAP) {
        for (int e = ebeg + t; e < eend; e += 256) {
            int2 m = smeta[e];
            int l = m.x >> COL_BITS;
            int p = atomicAdd(&cur[l], 1);
            stage[p] = make_int2(m.x & ((1 << COL_BITS) - 1), m.y);
        }
        __syncthreads();
        for (int i = t; i < nbe; i += 256)
            perm[ebeg + i] = stage[i];
    } else {
        for (int e = ebeg + t; e < eend; e += 256) {
            int2 m = smeta[e];
            int l = m.x >> COL_BITS;
            int p = atomicAdd(&cur[l], 1);
            perm[ebeg + p] = make_int2(m.x & ((1 << COL_BITS) - 1), m.y);
        }
    }
}

// ---------- batch accumulator init (float4, from fp32 embeddings) ----------
__global__ void init_bacc_kernel(const float* __restrict__ ue, const float* __restrict__ ie,
                                 const int* __restrict__ uids, const int* __restrict__ iids,
                                 float* __restrict__ uacc, float* __restrict__ iacc, int batch) {
    int t = blockIdx.x * blockDim.x + threadIdx.x;
    if (t >= batch * 16) return;
    int b = t >> 4;
    int q = t & 15;
    const float4* ue4 = (const float4*)ue;
    const float4* ie4 = (const float4*)ie;
    ((float4*)uacc)[t] = ue4[(long)uids[b] * 16 + q];
    ((float4*)iacc)[t] = ie4[(long)iids[b] * 16 + q];
}

// ---------- fp16 CSR gather SpMM: one wave per row, 8 edge-slots x 8 dim-lanes ----------
// 16 edges per iteration (2 independent groups). 32-bit byte-offset addressing
// (saddr + u32 voffset form). fp32 accumulate, fp16 store.
__global__ __launch_bounds__(256) void spmm_csr_h_kernel(
    const int* __restrict__ row_ptr, const int2* __restrict__ perm,
    const _Float16* __restrict__ x, _Float16* __restrict__ y, int n_nodes) {
    int lane = threadIdx.x & 63;
    int row = (blockIdx.x * blockDim.x + threadIdx.x) >> 6;
    if (row >= n_nodes) return;
    int start = row_ptr[row];
    int end   = row_ptr[row + 1];
    int sub  = lane >> 3;    // edge slot 0..7
    unsigned dimb = ((unsigned)(lane & 7)) << 4;   // byte offset of half8 within row
    const char* xb = reinterpret_cast<const char*>(x);
    float acc0[8], acc1[8];
    #pragma unroll
    for (int k = 0; k < 8; ++k) { acc0[k] = 0.f; acc1[k] = 0.f; }
    for (int base = start; base < end; base += 16) {
        int e0 = base + sub;
        int e1 = e0 + 8;
        int2 p0 = (e0 < end) ? perm[e0] : make_int2(0, 0);
        int2 p1 = (e1 < end) ? perm[e1] : make_int2(0, 0);
        float v0 = __int_as_float(p0.y);
        float v1 = __int_as_float(p1.y);
        h8v xv0 = *reinterpret_cast<const h8v*>(xb + ((((unsigned)p0.x) << 7) | dimb));
        h8v xv1 = *reinterpret_cast<const h8v*>(xb + ((((unsigned)p1.x) << 7) | dimb));
        #pragma unroll
        for (int k = 0; k < 8; ++k) acc0[k] = fmaf(v0, (float)xv0[k], acc0[k]);
        #pragma unroll
        for (int k = 0; k < 8; ++k) acc1[k] = fmaf(v1, (float)xv1[k], acc1[k]);
    }
    float accf[8];
    #pragma unroll
    for (int k = 0; k < 8; ++k) accf[k] = acc0[k] + acc1[k];
    #pragma unroll
    for (int off = 8; off < 64; off <<= 1) {
        #pragma unroll
        for (int k = 0; k < 8; ++k) accf[k] += __shfl_xor(accf[k], off);
    }
    if (sub == 0) {
        h8v o;
        #pragma unroll
        for (int k = 0; k < 8; ++k) o[k] = (_Float16)accf[k];
        *reinterpret_cast<h8v*>(reinterpret_cast<char*>(y) + ((((unsigned)row) << 7) | dimb)) = o;
    }
}

// ---------- layer-3 batch-restricted SpMM (fp16 x), accumulate into fp32 acc ----------
__global__ __launch_bounds__(256) void spmm_batch_h_kernel(
    const int* __restrict__ row_ptr, const int2* __restrict__ perm,
    const _Float16* __restrict__ x,
    const int* __restrict__ uids, const int* __restrict__ iids,
    float* __restrict__ uacc, float* __restrict__ iacc,
    int batch, int num_users) {
    int lane = threadIdx.x & 63;
    int w = (blockIdx.x * blockDim.x + threadIdx.x) >> 6;
    if (w >= 2 * batch) return;
    int row;
    float* target;
    if (w < batch) { row = uids[w];                     target = uacc + (long)w * EMBED_DIM; }
    else           { row = num_users + iids[w - batch]; target = iacc + (long)(w - batch) * EMBED_DIM; }
    int start = row_ptr[row];
    int end   = row_ptr[row + 1];
    int sub  = lane >> 3;
    int dimq = lane & 7;
    unsigned dimb = ((unsigned)dimq) << 4;
    const char* xb = reinterpret_cast<const char*>(x);
    float acc0[8], acc1[8];
    #pragma unroll
    for (int k = 0; k < 8; ++k) { acc0[k] = 0.f; acc1[k] = 0.f; }
    for (int base = start; base < end; base += 16) {
        int e0 = base + sub;
        int e1 = e0 + 8;
        int2 p0 = (e0 < end) ? perm[e0] : make_int2(0, 0);
        int2 p1 = (e1 < end) ? perm[e1] : make_int2(0, 0);
        float v0 = __int_as_float(p0.y);
        float v1 = __int_as_float(p1.y);
        h8v xv0 = *reinterpret_cast<const h8v*>(xb + ((((unsigned)p0.x) << 7) | dimb));
        h8v xv1 = *reinterpret_cast<const h8v*>(xb + ((((unsigned)p1.x) << 7) | dimb));
        #pragma unroll
        for (int k = 0; k < 8; ++k) acc0[k] = fmaf(v0, (float)xv0[k], acc0[k]);
        #pragma unroll
        for (int k = 0; k < 8; ++k) acc1[k] = fmaf(v1, (float)xv1[k], acc1[k]);
    }
    float accf[8];
    #pragma unroll
    for (int k = 0; k < 8; ++k) accf[k] = acc0[k] + acc1[k];
    #pragma unroll
    for (int off = 8; off < 64; off <<= 1) {
        #pragma unroll
        for (int k = 0; k < 8; ++k) accf[k] += __shfl_xor(accf[k], off);
    }
    if (sub == 0) {
        fx4* t4 = reinterpret_cast<fx4*>(target) + dimq * 2;
        fx4 lo = t4[0], hi = t4[1];
        lo.x += accf[0]; lo.y += accf[1]; lo.z += accf[2]; lo.w += accf[3];
        hi.x += accf[4]; hi.y += accf[5]; hi.z += accf[6]; hi.w += accf[7];
        t4[0] = lo; t4[1] = hi;
    }
}

// ---------- per-layer batch accumulate: fp16 y -> fp32 acc ----------
__global__ void bacc_add_h_kernel(const _Float16* __restrict__ y,
                                  const int* __restrict__ uids, const int* __restrict__ iids,
                                  float* __restrict__ uacc, float* __restrict__ iacc,
                                  int batch, int num_users) {
    int t = blockIdx.x * blockDim.x + threadIdx.x;
    if (t >= batch * 8) return;
    int b = t >> 3;
    int q = t & 7;
    const h8v* y8 = (const h8v*)y;
    h8v u = y8[(long)uids[b] * 8 + q];
    h8v v = y8[((long)num_users + iids[b]) * 8 + q];
    float4* ua = (float4*)uacc + (long)b * 16 + q * 2;
    float4* ia = (float4*)iacc + (long)b * 16 + q * 2;
    float4 a0 = ua[0], a1 = ua[1];
    a0.x += (float)u[0]; a0.y += (float)u[1]; a0.z += (float)u[2]; a0.w += (float)u[3];
    a1.x += (float)u[4]; a1.y += (float)u[5]; a1.z += (float)u[6]; a1.w += (float)u[7];
    ua[0] = a0; ua[1] = a1;
    float4 c0 = ia[0], c1 = ia[1];
    c0.x += (float)v[0]; c0.y += (float)v[1]; c0.z += (float)v[2]; c0.w += (float)v[3];
    c1.x += (float)v[4]; c1.y += (float)v[5]; c1.z += (float)v[6]; c1.w += (float)v[7];
    ia[0] = c0; ia[1] = c1;
}

// ---------- scoring ----------
__global__ void score_kernel(const float* __restrict__ uacc, const float* __restrict__ iacc,
                             float* __restrict__ out, int batch) {
    int lane = threadIdx.x & 63;
    int w = (blockIdx.x * blockDim.x + threadIdx.x) >> 6;
    if (w >= batch) return;
    float p = uacc[(long)w * EMBED_DIM + lane] * iacc[(long)w * EMBED_DIM + lane];
    #pragma unroll
    for (int off = 32; off > 0; off >>= 1) p += __shfl_down(p, off);
    if (lane == 0) out[w] = p * (1.0f / 16.0f);  // (acc/4)·(acc/4)
}

extern "C" void kernel_launch(void* const* d_in, const int* in_sizes, int n_in,
                              void* d_out, int out_size, void* d_ws, size_t ws_size,
                              hipStream_t stream) {
    const float* user_emb = (const float*)d_in[0];
    const float* item_emb = (const float*)d_in[1];
    const int*   adj_rows = (const int*)d_in[2];
    const int*   adj_cols = (const int*)d_in[3];
    const float* adj_vals = (const float*)d_in[4];
    const int*   user_ids = (const int*)d_in[5];
    const int*   item_ids = (const int*)d_in[6];
    float* out = (float*)d_out;

    const int num_users = in_sizes[0] / EMBED_DIM;   // 200000
    const int num_items = in_sizes[1] / EMBED_DIM;   // 100000
    const int n_nodes   = num_users + num_items;     // 300000
    const int nnz       = in_sizes[2];               // 6000000
    const int batch     = in_sizes[5];               // 16384

    const long node_elems = (long)n_nodes * EMBED_DIM;    // 19.2M elems
    const long bacc_elems = (long)batch * EMBED_DIM;      // 1.05M floats

    const int nbuck = (n_nodes + BUCKET_ROWS - 1) >> BUCKET_SHIFT;   // 586
    const int nscan = nbuck * NBLK_A;                                // 150016
    const int nscan_blocks = (nscan + SCAN2_CHUNK - 1) / SCAN2_CHUNK; // 74

    // ---- workspace layout ----
    char* wp = (char*)d_ws;
    _Float16* xh   = (_Float16*)wp;      wp += node_elems * sizeof(_Float16);
    _Float16* bufA = (_Float16*)wp;      wp += node_elems * sizeof(_Float16);
    _Float16* bufB = (_Float16*)wp;      wp += node_elems * sizeof(_Float16);
    float* uacc = (float*)wp;            wp += bacc_elems * sizeof(float);
    float* iacc = (float*)wp;            wp += bacc_elems * sizeof(float);
    int*   row_ptr = (int*)wp;           wp += (size_t)(n_nodes + 4) * sizeof(int);
    int*   bsum    = (int*)wp;           wp += 512 * sizeof(int);
    int*   boff    = (int*)wp;           wp += 512 * sizeof(int);
    int*   blockCounts = (int*)wp;       wp += (size_t)nscan * sizeof(int);
    int*   scanOut     = (int*)wp;       wp += (size_t)nscan * sizeof(int);
    wp = (char*)(((uintptr_t)wp + 15) & ~(uintptr_t)15);
    int2*  perm    = (int2*)wp;          wp += (size_t)nnz * sizeof(int2);

    // smeta staging (48 MB) overlays bufA+bufB (76.8 MB contiguous): both are
    // first written by spmm layers, which run after bucket_build consumes smeta.
    int2* smeta = (int2*)bufA;

    const int chunkA = (((nnz + NBLK_A - 1) / NBLK_A) + 1023) & ~1023;   // 24576

    // ---- radix CSR build (no device atomics) ----
    bucket_count_kernel<<<NBLK_A, 256, 0, stream>>>(adj_rows, blockCounts, nnz, nbuck, chunkA);
    scan8_phase1<<<nscan_blocks, 256, 0, stream>>>(blockCounts, bsum, nscan);
    scan_phase2<<<1, 512, 0, stream>>>(bsum, boff, nscan_blocks);
    scan8_phase3<<<nscan_blocks, 256, 0, stream>>>(blockCounts, boff, scanOut, nscan);
    bucket_scatter_kernel<<<NBLK_A, 256, 0, stream>>>(adj_rows, adj_cols, adj_vals,
                                                      scanOut, smeta, nnz, nbuck, chunkA);
    bucket_build_kernel<<<nbuck, 256, 0, stream>>>(smeta, scanOut, perm,
                                                   row_ptr, nnz, n_nodes, nbuck);

    // ---- convert x0 to fp16 ----
    convert_x_kernel<<<2048, 256, 0, stream>>>(user_emb, item_emb, xh,
                                               num_users * EMBED_DIM, (int)node_elems);

    // ---- batch accumulator init (layer-0 term, fp32) ----
    {
        int blocks = (batch * 16 + 255) / 256;
        init_bacc_kernel<<<blocks, 256, 0, stream>>>(user_emb, item_emb, user_ids, item_ids,
                                                     uacc, iacc, batch);
    }

    const int spmm_blocks = ((n_nodes * 64) + 255) / 256;   // one wave per row
    const int bblocks = (batch * 8 + 255) / 256;

    // ---- layer 1: xh -> bufA ----
    spmm_csr_h_kernel<<<spmm_blocks, 256, 0, stream>>>(row_ptr, perm, xh, bufA, n_nodes);
    bacc_add_h_kernel<<<bblocks, 256, 0, stream>>>(bufA, user_ids, item_ids,
                                                   uacc, iacc, batch, num_users);

    // ---- layer 2: bufA -> bufB ----
    spmm_csr_h_kernel<<<spmm_blocks, 256, 0, stream>>>(row_ptr, perm, bufA, bufB, n_nodes);
    bacc_add_h_kernel<<<bblocks, 256, 0, stream>>>(bufB, user_ids, item_ids,
                                                   uacc, iacc, batch, num_users);

    // ---- layer 3 (batch-restricted): bufB -> uacc/iacc directly ----
    {
        int waves = 2 * batch;                        // 32768 waves
        int blocks = (waves * 64 + 255) / 256;        // 8192 blocks
        spmm_batch_h_kernel<<<blocks, 256, 0, stream>>>(row_ptr, perm, bufB,
                                                        user_ids, item_ids,
                                                        uacc, iacc, batch, num_users);
    }

    // ---- score ----
    {
        int blocks = (batch * 64 + 255) / 256;
        score_kernel<<<blocks, 256, 0, stream>>>(uacc, iacc, out, batch);
    }
}

// Round 12
// 495.363 us; speedup vs baseline: 1.0457x; 1.0042x over previous
//
#include <hip/hip_runtime.h>

#define EMBED_DIM 64
#define NBLK_A 256            // blocks in bucket count/scatter passes
#define BUCKET_SHIFT 9        // 512 rows per bucket
#define BUCKET_ROWS 512
#define MAX_NBUCK 640
#define SCAN2_CHUNK 2048      // 256 threads x 8
#define COL_BITS 19           // col < 2^19; meta = (localrow << 19) | col
#define STAGE_CAP 15360       // LDS staging capacity (120 KB)

typedef float fx4 __attribute__((ext_vector_type(4)));
typedef int   ix4 __attribute__((ext_vector_type(4)));
typedef float fv4 __attribute__((ext_vector_type(4)));
typedef _Float16 h8v __attribute__((ext_vector_type(8)));

// ---------- convert concat(user_emb, item_emb) fp32 -> fp16 ----------
__global__ void convert_x_kernel(const float* __restrict__ ue, const float* __restrict__ ie,
                                 _Float16* __restrict__ xh, int nu_elems, int total) {
    int i = blockIdx.x * blockDim.x + threadIdx.x;   // index in units of 8 elems
    int stride = gridDim.x * blockDim.x;
    int n8 = total >> 3;
    int nu8 = nu_elems >> 3;
    for (; i < n8; i += stride) {
        const float4* src = (i < nu8) ? (const float4*)(ue) + 2 * i
                                      : (const float4*)(ie) + 2 * (i - nu8);
        float4 lo = src[0];
        float4 hi = src[1];
        h8v o;
        o[0] = (_Float16)lo.x; o[1] = (_Float16)lo.y;
        o[2] = (_Float16)lo.z; o[3] = (_Float16)lo.w;
        o[4] = (_Float16)hi.x; o[5] = (_Float16)hi.y;
        o[6] = (_Float16)hi.z; o[7] = (_Float16)hi.w;
        reinterpret_cast<h8v*>(xh)[i] = o;
    }
}

// ---------- pass A1: per-block bucket histogram (LDS), bucket-major dump ----------
__global__ __launch_bounds__(256) void bucket_count_kernel(
    const int* __restrict__ rows, int* __restrict__ blockCounts,
    int nnz, int nbuck, int chunk) {
    __shared__ int hist[MAX_NBUCK];
    int t = threadIdx.x, blk = blockIdx.x;
    for (int i = t; i < nbuck; i += 256) hist[i] = 0;
    __syncthreads();
    int e0 = blk * chunk;
    int e1 = min(e0 + chunk, nnz);
    for (int e = e0 + t * 4; e < e1; e += 1024) {
        ix4 r4 = __builtin_nontemporal_load(reinterpret_cast<const ix4*>(rows + e));
        atomicAdd(&hist[r4.x >> BUCKET_SHIFT], 1);
        atomicAdd(&hist[r4.y >> BUCKET_SHIFT], 1);
        atomicAdd(&hist[r4.z >> BUCKET_SHIFT], 1);
        atomicAdd(&hist[r4.w >> BUCKET_SHIFT], 1);
    }
    __syncthreads();
    for (int u = t; u < nbuck; u += 256)
        blockCounts[u * NBLK_A + blk] = hist[u];
}

// ---------- scan phase 1 (chunk 2048): per-block sums ----------
__global__ void scan8_phase1(const int* __restrict__ in, int* __restrict__ bsum, int n) {
    __shared__ int wsum[4];
    int t = threadIdx.x, b = blockIdx.x;
    int i0 = b * SCAN2_CHUNK + t * 8;
    int s = 0;
    #pragma unroll
    for (int k = 0; k < 8; ++k) { int i = i0 + k; if (i < n) s += in[i]; }
    #pragma unroll
    for (int off = 1; off < 64; off <<= 1) s += __shfl_xor(s, off);
    if ((t & 63) == 0) wsum[t >> 6] = s;
    __syncthreads();
    if (t == 0) bsum[b] = wsum[0] + wsum[1] + wsum[2] + wsum[3];
}

// ---------- scan phase 2: single-block scan of block sums (nb <= 512) ----------
__global__ void scan_phase2(const int* __restrict__ bsum, int* __restrict__ boff, int nb) {
    __shared__ int lds[512];
    int t = threadIdx.x;
    lds[t] = (t < nb) ? bsum[t] : 0;
    __syncthreads();
    for (int off = 1; off < 512; off <<= 1) {
        int v = (t >= off) ? lds[t - off] : 0;
        __syncthreads();
        lds[t] += v;
        __syncthreads();
    }
    if (t < nb) boff[t] = (t == 0) ? 0 : lds[t - 1];
}

// ---------- scan phase 3 (chunk 2048): write exclusive prefix ----------
__global__ void scan8_phase3(const int* __restrict__ in, const int* __restrict__ boff,
                             int* __restrict__ out, int n) {
    __shared__ int wexcl[4];
    int t = threadIdx.x, b = blockIdx.x;
    int lane = t & 63, w = t >> 6;
    int i0 = b * SCAN2_CHUNK + t * 8;
    int c[8];
    int s = 0;
    #pragma unroll
    for (int k = 0; k < 8; ++k) { int i = i0 + k; c[k] = (i < n) ? in[i] : 0; s += c[k]; }
    int incl = s;
    #pragma unroll
    for (int off = 1; off < 64; off <<= 1) {
        int u = __shfl_up(incl, off);
        if (lane >= off) incl += u;
    }
    if (lane == 63) wexcl[w] = incl;
    __syncthreads();
    int wbase = 0;
    for (int ww = 0; ww < w; ++ww) wbase += wexcl[ww];
    int run = incl - s + wbase + boff[b];
    #pragma unroll
    for (int k = 0; k < 8; ++k) {
        int i = i0 + k;
        if (i < n) { out[i] = run; run += c[k]; }
    }
}

// ---------- pass A3: scatter edges into bucket-partitioned staging (LDS cursors) ----------
__global__ __launch_bounds__(256) void bucket_scatter_kernel(
    const int* __restrict__ rows, const int* __restrict__ cols,
    const float* __restrict__ vals, const int* __restrict__ scanOut,
    int2* __restrict__ smeta, int nnz, int nbuck, int chunk) {
    __shared__ int cur[MAX_NBUCK];
    int t = threadIdx.x, blk = blockIdx.x;
    for (int u = t; u < nbuck; u += 256) cur[u] = scanOut[u * NBLK_A + blk];
    __syncthreads();
    int e0 = blk * chunk;
    int e1 = min(e0 + chunk, nnz);
    for (int e = e0 + t * 4; e < e1; e += 1024) {
        ix4 r4 = __builtin_nontemporal_load(reinterpret_cast<const ix4*>(rows + e));
        ix4 c4 = __builtin_nontemporal_load(reinterpret_cast<const ix4*>(cols + e));
        fv4 v4 = __builtin_nontemporal_load(reinterpret_cast<const fv4*>(vals + e));
        int p0 = atomicAdd(&cur[r4.x >> BUCKET_SHIFT], 1);
        smeta[p0] = make_int2(((r4.x & (BUCKET_ROWS - 1)) << COL_BITS) | c4.x, __float_as_int(v4.x));
        int p1 = atomicAdd(&cur[r4.y >> BUCKET_SHIFT], 1);
        smeta[p1] = make_int2(((r4.y & (BUCKET_ROWS - 1)) << COL_BITS) | c4.y, __float_as_int(v4.y));
        int p2 = atomicAdd(&cur[r4.z >> BUCKET_SHIFT], 1);
        smeta[p2] = make_int2(((r4.z & (BUCKET_ROWS - 1)) << COL_BITS) | c4.z, __float_as_int(v4.z));
        int p3 = atomicAdd(&cur[r4.w >> BUCKET_SHIFT], 1);
        smeta[p3] = make_int2(((r4.w & (BUCKET_ROWS - 1)) << COL_BITS) | c4.w, __float_as_int(v4.w));
    }
}

// ---------- pass B: per-bucket counting sort -> row_ptr + perm (LDS-staged) ----------
__global__ __launch_bounds__(256) void bucket_build_kernel(
    const int2* __restrict__ smeta, const int* __restrict__ scanOut,
    int2* __restrict__ perm, int* __restrict__ row_ptr,
    int nnz, int n_nodes, int nbuck) {
    __shared__ int hist[BUCKET_ROWS], excl[BUCKET_ROWS], cur[BUCKET_ROWS];
    __shared__ int wex[4];
    __shared__ int2 stage[STAGE_CAP];
    int t = threadIdx.x, b = blockIdx.x;
    int lane = t & 63, w = t >> 6;
    int ebeg = scanOut[b * NBLK_A];
    int eend = (b + 1 < nbuck) ? scanOut[(b + 1) * NBLK_A] : nnz;
    hist[t] = 0; hist[t + 256] = 0;
    __syncthreads();
    for (int e = ebeg + t; e < eend; e += 256)
        atomicAdd(&hist[smeta[e].x >> COL_BITS], 1);
    __syncthreads();
    int a = hist[2 * t], bcnt = hist[2 * t + 1];
    int s = a + bcnt;
    int incl = s;
    #pragma unroll
    for (int off = 1; off < 64; off <<= 1) {
        int u = __shfl_up(incl, off);
        if (lane >= off) incl += u;
    }
    if (lane == 63) wex[w] = incl;
    __syncthreads();
    int wbase = 0;
    for (int ww = 0; ww < w; ++ww) wbase += wex[ww];
    int es = wbase + incl - s;
    excl[2 * t] = es;
    excl[2 * t + 1] = es + a;
    cur[2 * t] = es;
    cur[2 * t + 1] = es + a;
    __syncthreads();
    int base_row = b << BUCKET_SHIFT;
    for (int r = t; r < BUCKET_ROWS; r += 256) {
        int gr = base_row + r;
        if (gr < n_nodes) row_ptr[gr] = ebeg + excl[r];
    }
    if (b == 0 && t == 0) row_ptr[n_nodes] = nnz;
    int nbe = eend - ebeg;
    if (nbe <= STAGE_CAP) {
        for (int e = ebeg + t; e < eend; e += 256) {
            int2 m = smeta[e];
            int l = m.x >> COL_BITS;
            int p = atomicAdd(&cur[l], 1);
            stage[p] = make_int2(m.x & ((1 << COL_BITS) - 1), m.y);
        }
        __syncthreads();
        for (int i = t; i < nbe; i += 256)
            perm[ebeg + i] = stage[i];
    } else {
        for (int e = ebeg + t; e < eend; e += 256) {
            int2 m = smeta[e];
            int l = m.x >> COL_BITS;
            int p = atomicAdd(&cur[l], 1);
            perm[ebeg + p] = make_int2(m.x & ((1 << COL_BITS) - 1), m.y);
        }
    }
}

// ---------- batch accumulator init (float4, from fp32 embeddings) ----------
__global__ void init_bacc_kernel(const float* __restrict__ ue, const float* __restrict__ ie,
                                 const int* __restrict__ uids, const int* __restrict__ iids,
                                 float* __restrict__ uacc, float* __restrict__ iacc, int batch) {
    int t = blockIdx.x * blockDim.x + threadIdx.x;
    if (t >= batch * 16) return;
    int b = t >> 4;
    int q = t & 15;
    const float4* ue4 = (const float4*)ue;
    const float4* ie4 = (const float4*)ie;
    ((float4*)uacc)[t] = ue4[(long)uids[b] * 16 + q];
    ((float4*)iacc)[t] = ie4[(long)iids[b] * 16 + q];
}

// ---------- mark nodes whose layer-2 output is actually consumed ----------
// needed = { uid/iid rows } ∪ { cols of their edges }. Byte stores, races benign.
__global__ __launch_bounds__(256) void mark_needed_kernel(
    const int* __restrict__ row_ptr, const int2* __restrict__ perm,
    const int* __restrict__ uids, const int* __restrict__ iids,
    char* __restrict__ needed, int batch, int num_users) {
    int lane = threadIdx.x & 63;
    int w = (blockIdx.x * blockDim.x + threadIdx.x) >> 6;
    if (w >= 2 * batch) return;
    int row = (w < batch) ? uids[w] : num_users + iids[w - batch];
    if (lane == 0) needed[row] = 1;
    int start = row_ptr[row];
    int end   = row_ptr[row + 1];
    for (int e = start + lane; e < end; e += 64)
        needed[perm[e].x] = 1;
}

// ---------- fp16 CSR gather SpMM: one wave per row, 8 edge-slots x 8 dim-lanes ----------
// 24 edges per iteration (3 independent groups, round-9-style cheap guards).
// Optional needed[] filter (wave-uniform early-out). fp32 accumulate, fp16 store.
__global__ __launch_bounds__(256) void spmm_csr_h_kernel(
    const int* __restrict__ row_ptr, const int2* __restrict__ perm,
    const _Float16* __restrict__ x, _Float16* __restrict__ y,
    const char* __restrict__ needed, int n_nodes) {
    int lane = threadIdx.x & 63;
    int row = (blockIdx.x * blockDim.x + threadIdx.x) >> 6;
    if (row >= n_nodes) return;
    if (needed && !needed[row]) return;
    int start = row_ptr[row];
    int end   = row_ptr[row + 1];
    int sub  = lane >> 3;    // edge slot 0..7
    unsigned dimb = ((unsigned)(lane & 7)) << 4;   // byte offset of half8 within row
    const char* xb = reinterpret_cast<const char*>(x);
    float acc0[8], acc1[8], acc2[8];
    #pragma unroll
    for (int k = 0; k < 8; ++k) { acc0[k] = 0.f; acc1[k] = 0.f; acc2[k] = 0.f; }
    for (int base = start; base < end; base += 24) {
        int e0 = base + sub;
        int e1 = e0 + 8;
        int e2 = e0 + 16;
        int2 p0 = (e0 < end) ? perm[e0] : make_int2(0, 0);
        int2 p1 = (e1 < end) ? perm[e1] : make_int2(0, 0);
        int2 p2 = (e2 < end) ? perm[e2] : make_int2(0, 0);
        float v0 = __int_as_float(p0.y);
        float v1 = __int_as_float(p1.y);
        float v2 = __int_as_float(p2.y);
        h8v xv0 = *reinterpret_cast<const h8v*>(xb + ((((unsigned)p0.x) << 7) | dimb));
        h8v xv1 = *reinterpret_cast<const h8v*>(xb + ((((unsigned)p1.x) << 7) | dimb));
        h8v xv2 = *reinterpret_cast<const h8v*>(xb + ((((unsigned)p2.x) << 7) | dimb));
        #pragma unroll
        for (int k = 0; k < 8; ++k) acc0[k] = fmaf(v0, (float)xv0[k], acc0[k]);
        #pragma unroll
        for (int k = 0; k < 8; ++k) acc1[k] = fmaf(v1, (float)xv1[k], acc1[k]);
        #pragma unroll
        for (int k = 0; k < 8; ++k) acc2[k] = fmaf(v2, (float)xv2[k], acc2[k]);
    }
    float accf[8];
    #pragma unroll
    for (int k = 0; k < 8; ++k) accf[k] = acc0[k] + acc1[k] + acc2[k];
    #pragma unroll
    for (int off = 8; off < 64; off <<= 1) {
        #pragma unroll
        for (int k = 0; k < 8; ++k) accf[k] += __shfl_xor(accf[k], off);
    }
    if (sub == 0) {
        h8v o;
        #pragma unroll
        for (int k = 0; k < 8; ++k) o[k] = (_Float16)accf[k];
        *reinterpret_cast<h8v*>(reinterpret_cast<char*>(y) + ((((unsigned)row) << 7) | dimb)) = o;
    }
}

// ---------- fused layer-3 batch SpMM + scoring ----------
// One wave per batch element: compute layer-3 sums for its u-row and i-row,
// add the preloaded layer-0..2 accumulators, dot, write out[b].
__global__ __launch_bounds__(256) void spmm_batch_score_kernel(
    const int* __restrict__ row_ptr, const int2* __restrict__ perm,
    const _Float16* __restrict__ x,
    const int* __restrict__ uids, const int* __restrict__ iids,
    const float* __restrict__ uacc, const float* __restrict__ iacc,
    float* __restrict__ out, int batch, int num_users) {
    int lane = threadIdx.x & 63;
    int b = (blockIdx.x * blockDim.x + threadIdx.x) >> 6;
    if (b >= batch) return;
    int sub  = lane >> 3;
    int dimq = lane & 7;
    unsigned dimb = ((unsigned)dimq) << 4;
    const char* xb = reinterpret_cast<const char*>(x);
    float u3[8], i3[8];
    #pragma unroll
    for (int k = 0; k < 8; ++k) { u3[k] = 0.f; i3[k] = 0.f; }
    // --- u row ---
    {
        int row = uids[b];
        int start = row_ptr[row];
        int end   = row_ptr[row + 1];
        for (int base = start; base < end; base += 16) {
            int e0 = base + sub;
            int e1 = e0 + 8;
            int2 p0 = (e0 < end) ? perm[e0] : make_int2(0, 0);
            int2 p1 = (e1 < end) ? perm[e1] : make_int2(0, 0);
            float v0 = __int_as_float(p0.y);
            float v1 = __int_as_float(p1.y);
            h8v xv0 = *reinterpret_cast<const h8v*>(xb + ((((unsigned)p0.x) << 7) | dimb));
            h8v xv1 = *reinterpret_cast<const h8v*>(xb + ((((unsigned)p1.x) << 7) | dimb));
            #pragma unroll
            for (int k = 0; k < 8; ++k) u3[k] = fmaf(v0, (float)xv0[k], u3[k]);
            #pragma unroll
            for (int k = 0; k < 8; ++k) u3[k] = fmaf(v1, (float)xv1[k], u3[k]);
        }
    }
    // --- i row ---
    {
        int row = num_users + iids[b];
        int start = row_ptr[row];
        int end   = row_ptr[row + 1];
        for (int base = start; base < end; base += 16) {
            int e0 = base + sub;
            int e1 = e0 + 8;
            int2 p0 = (e0 < end) ? perm[e0] : make_int2(0, 0);
            int2 p1 = (e1 < end) ? perm[e1] : make_int2(0, 0);
            float v0 = __int_as_float(p0.y);
            float v1 = __int_as_float(p1.y);
            h8v xv0 = *reinterpret_cast<const h8v*>(xb + ((((unsigned)p0.x) << 7) | dimb));
            h8v xv1 = *reinterpret_cast<const h8v*>(xb + ((((unsigned)p1.x) << 7) | dimb));
            #pragma unroll
            for (int k = 0; k < 8; ++k) i3[k] = fmaf(v0, (float)xv0[k], i3[k]);
            #pragma unroll
            for (int k = 0; k < 8; ++k) i3[k] = fmaf(v1, (float)xv1[k], i3[k]);
        }
    }
    // reduce across the 8 edge slots (lane bits 3,4,5)
    #pragma unroll
    for (int off = 8; off < 64; off <<= 1) {
        #pragma unroll
        for (int k = 0; k < 8; ++k) {
            u3[k] += __shfl_xor(u3[k], off);
            i3[k] += __shfl_xor(i3[k], off);
        }
    }
    // add layer-0..2 accumulators and dot
    const fx4* ua = reinterpret_cast<const fx4*>(uacc + (long)b * EMBED_DIM) + dimq * 2;
    const fx4* ia = reinterpret_cast<const fx4*>(iacc + (long)b * EMBED_DIM) + dimq * 2;
    fx4 ulo = ua[0], uhi = ua[1];
    fx4 ilo = ia[0], ihi = ia[1];
    float s = 0.f;
    s += (ulo.x + u3[0]) * (ilo.x + i3[0]);
    s += (ulo.y + u3[1]) * (ilo.y + i3[1]);
    s += (ulo.z + u3[2]) * (ilo.z + i3[2]);
    s += (ulo.w + u3[3]) * (ilo.w + i3[3]);
    s += (uhi.x + u3[4]) * (ihi.x + i3[4]);
    s += (uhi.y + u3[5]) * (ihi.y + i3[5]);
    s += (uhi.z + u3[6]) * (ihi.z + i3[6]);
    s += (uhi.w + u3[7]) * (ihi.w + i3[7]);
    #pragma unroll
    for (int off = 1; off < 8; off <<= 1) s += __shfl_xor(s, off);
    if (lane == 0) out[b] = s * (1.0f / 16.0f);  // (acc/4)·(acc/4)
}

// ---------- per-layer batch accumulate: fp16 y -> fp32 acc ----------
__global__ void bacc_add_h_kernel(const _Float16* __restrict__ y,
                                  const int* __restrict__ uids, const int* __restrict__ iids,
                                  float* __restrict__ uacc, float* __restrict__ iacc,
                                  int batch, int num_users) {
    int t = blockIdx.x * blockDim.x + threadIdx.x;
    if (t >= batch * 8) return;
    int b = t >> 3;
    int q = t & 7;
    const h8v* y8 = (const h8v*)y;
    h8v u = y8[(long)uids[b] * 8 + q];
    h8v v = y8[((long)num_users + iids[b]) * 8 + q];
    float4* ua = (float4*)uacc + (long)b * 16 + q * 2;
    float4* ia = (float4*)iacc + (long)b * 16 + q * 2;
    float4 a0 = ua[0], a1 = ua[1];
    a0.x += (float)u[0]; a0.y += (float)u[1]; a0.z += (float)u[2]; a0.w += (float)u[3];
    a1.x += (float)u[4]; a1.y += (float)u[5]; a1.z += (float)u[6]; a1.w += (float)u[7];
    ua[0] = a0; ua[1] = a1;
    float4 c0 = ia[0], c1 = ia[1];
    c0.x += (float)v[0]; c0.y += (float)v[1]; c0.z += (float)v[2]; c0.w += (float)v[3];
    c1.x += (float)v[4]; c1.y += (float)v[5]; c1.z += (float)v[6]; c1.w += (float)v[7];
    ia[0] = c0; ia[1] = c1;
}

extern "C" void kernel_launch(void* const* d_in, const int* in_sizes, int n_in,
                              void* d_out, int out_size, void* d_ws, size_t ws_size,
                              hipStream_t stream) {
    const float* user_emb = (const float*)d_in[0];
    const float* item_emb = (const float*)d_in[1];
    const int*   adj_rows = (const int*)d_in[2];
    const int*   adj_cols = (const int*)d_in[3];
    const float* adj_vals = (const float*)d_in[4];
    const int*   user_ids = (const int*)d_in[5];
    const int*   item_ids = (const int*)d_in[6];
    float* out = (float*)d_out;

    const int num_users = in_sizes[0] / EMBED_DIM;   // 200000
    const int num_items = in_sizes[1] / EMBED_DIM;   // 100000
    const int n_nodes   = num_users + num_items;     // 300000
    const int nnz       = in_sizes[2];               // 6000000
    const int batch     = in_sizes[5];               // 16384

    const long node_elems = (long)n_nodes * EMBED_DIM;    // 19.2M elems
    const long bacc_elems = (long)batch * EMBED_DIM;      // 1.05M floats

    const int nbuck = (n_nodes + BUCKET_ROWS - 1) >> BUCKET_SHIFT;   // 586
    const int nscan = nbuck * NBLK_A;                                // 150016
    const int nscan_blocks = (nscan + SCAN2_CHUNK - 1) / SCAN2_CHUNK; // 74

    // ---- workspace layout ----
    char* wp = (char*)d_ws;
    _Float16* xh   = (_Float16*)wp;      wp += node_elems * sizeof(_Float16);
    _Float16* bufA = (_Float16*)wp;      wp += node_elems * sizeof(_Float16);
    _Float16* bufB = (_Float16*)wp;      wp += node_elems * sizeof(_Float16);
    float* uacc = (float*)wp;            wp += bacc_elems * sizeof(float);
    float* iacc = (float*)wp;            wp += bacc_elems * sizeof(float);
    int*   row_ptr = (int*)wp;           wp += (size_t)(n_nodes + 4) * sizeof(int);
    int*   bsum    = (int*)wp;           wp += 512 * sizeof(int);
    int*   boff    = (int*)wp;           wp += 512 * sizeof(int);
    int*   blockCounts = (int*)wp;       wp += (size_t)nscan * sizeof(int);
    int*   scanOut     = (int*)wp;       wp += (size_t)nscan * sizeof(int);
    char*  needed      = wp;             wp += (size_t)n_nodes;
    wp = (char*)(((uintptr_t)wp + 15) & ~(uintptr_t)15);
    int2*  perm    = (int2*)wp;          wp += (size_t)nnz * sizeof(int2);

    // smeta staging (48 MB) overlays bufA+bufB (76.8 MB contiguous): both are
    // first written by spmm layers, which run after bucket_build consumes smeta.
    int2* smeta = (int2*)bufA;

    const int chunkA = (((nnz + NBLK_A - 1) / NBLK_A) + 1023) & ~1023;   // 24576

    // ---- radix CSR build (no device atomics) ----
    bucket_count_kernel<<<NBLK_A, 256, 0, stream>>>(adj_rows, blockCounts, nnz, nbuck, chunkA);
    scan8_phase1<<<nscan_blocks, 256, 0, stream>>>(blockCounts, bsum, nscan);
    scan_phase2<<<1, 512, 0, stream>>>(bsum, boff, nscan_blocks);
    scan8_phase3<<<nscan_blocks, 256, 0, stream>>>(blockCounts, boff, scanOut, nscan);
    bucket_scatter_kernel<<<NBLK_A, 256, 0, stream>>>(adj_rows, adj_cols, adj_vals,
                                                      scanOut, smeta, nnz, nbuck, chunkA);
    bucket_build_kernel<<<nbuck, 256, 0, stream>>>(smeta, scanOut, perm,
                                                   row_ptr, nnz, n_nodes, nbuck);

    // ---- convert x0 to fp16 ----
    convert_x_kernel<<<2048, 256, 0, stream>>>(user_emb, item_emb, xh,
                                               num_users * EMBED_DIM, (int)node_elems);

    // ---- batch accumulator init (layer-0 term, fp32) ----
    {
        int blocks = (batch * 16 + 255) / 256;
        init_bacc_kernel<<<blocks, 256, 0, stream>>>(user_emb, item_emb, user_ids, item_ids,
                                                     uacc, iacc, batch);
    }

    // ---- needed-set for layer 2 (batch rows + their neighbors) ----
    hipMemsetAsync(needed, 0, (size_t)n_nodes, stream);
    {
        int waves = 2 * batch;
        int blocks = (waves * 64 + 255) / 256;
        mark_needed_kernel<<<blocks, 256, 0, stream>>>(row_ptr, perm, user_ids, item_ids,
                                                       needed, batch, num_users);
    }

    const int spmm_blocks = ((n_nodes * 64) + 255) / 256;   // one wave per row
    const int bblocks = (batch * 8 + 255) / 256;

    // ---- layer 1: xh -> bufA (all rows) ----
    spmm_csr_h_kernel<<<spmm_blocks, 256, 0, stream>>>(row_ptr, perm, xh, bufA,
                                                       nullptr, n_nodes);
    bacc_add_h_kernel<<<bblocks, 256, 0, stream>>>(bufA, user_ids, item_ids,
                                                   uacc, iacc, batch, num_users);

    // ---- layer 2: bufA -> bufB (needed rows only) ----
    spmm_csr_h_kernel<<<spmm_blocks, 256, 0, stream>>>(row_ptr, perm, bufA, bufB,
                                                       needed, n_nodes);
    bacc_add_h_kernel<<<bblocks, 256, 0, stream>>>(bufB, user_ids, item_ids,
                                                   uacc, iacc, batch, num_users);

    // ---- layer 3 (batch-restricted) fused with scoring ----
    {
        int blocks = (batch * 64 + 255) / 256;       // one wave per batch element
        spmm_batch_score_kernel<<<blocks, 256, 0, stream>>>(row_ptr, perm, bufB,
                                                            user_ids, item_ids,
                                                            uacc, iacc, out,
                                                            batch, num_users);
    }
}

// Round 13
// 488.921 us; speedup vs baseline: 1.0595x; 1.0132x over previous
//
#include <hip/hip_runtime.h>

#define EMBED_DIM 64
#define NBLK_A 256            // blocks in bucket count/scatter passes
#define BUCKET_SHIFT 9        // 512 rows per bucket
#define BUCKET_ROWS 512
#define MAX_NBUCK 640
#define SCAN2_CHUNK 2048      // 256 threads x 8
#define COL_BITS 19           // col < 2^19; meta = (localrow << 19) | col
#define STAGE_CAP 15360       // LDS staging capacity (120 KB)

typedef float fx4 __attribute__((ext_vector_type(4)));
typedef int   ix4 __attribute__((ext_vector_type(4)));
typedef float fv4 __attribute__((ext_vector_type(4)));
typedef _Float16 h8v __attribute__((ext_vector_type(8)));

// ---------- convert concat(user_emb, item_emb) fp32 -> fp16 ----------
__global__ void convert_x_kernel(const float* __restrict__ ue, const float* __restrict__ ie,
                                 _Float16* __restrict__ xh, int nu_elems, int total) {
    int i = blockIdx.x * blockDim.x + threadIdx.x;   // index in units of 8 elems
    int stride = gridDim.x * blockDim.x;
    int n8 = total >> 3;
    int nu8 = nu_elems >> 3;
    for (; i < n8; i += stride) {
        const float4* src = (i < nu8) ? (const float4*)(ue) + 2 * i
                                      : (const float4*)(ie) + 2 * (i - nu8);
        float4 lo = src[0];
        float4 hi = src[1];
        h8v o;
        o[0] = (_Float16)lo.x; o[1] = (_Float16)lo.y;
        o[2] = (_Float16)lo.z; o[3] = (_Float16)lo.w;
        o[4] = (_Float16)hi.x; o[5] = (_Float16)hi.y;
        o[6] = (_Float16)hi.z; o[7] = (_Float16)hi.w;
        reinterpret_cast<h8v*>(xh)[i] = o;
    }
}

// ---------- pass A1: per-block bucket histogram (LDS), bucket-major dump ----------
__global__ __launch_bounds__(256) void bucket_count_kernel(
    const int* __restrict__ rows, int* __restrict__ blockCounts,
    int nnz, int nbuck, int chunk) {
    __shared__ int hist[MAX_NBUCK];
    int t = threadIdx.x, blk = blockIdx.x;
    for (int i = t; i < nbuck; i += 256) hist[i] = 0;
    __syncthreads();
    int e0 = blk * chunk;
    int e1 = min(e0 + chunk, nnz);
    for (int e = e0 + t * 4; e < e1; e += 1024) {
        ix4 r4 = __builtin_nontemporal_load(reinterpret_cast<const ix4*>(rows + e));
        atomicAdd(&hist[r4.x >> BUCKET_SHIFT], 1);
        atomicAdd(&hist[r4.y >> BUCKET_SHIFT], 1);
        atomicAdd(&hist[r4.z >> BUCKET_SHIFT], 1);
        atomicAdd(&hist[r4.w >> BUCKET_SHIFT], 1);
    }
    __syncthreads();
    for (int u = t; u < nbuck; u += 256)
        blockCounts[u * NBLK_A + blk] = hist[u];
}

// ---------- scan phase 1 (chunk 2048): per-block sums ----------
__global__ void scan8_phase1(const int* __restrict__ in, int* __restrict__ bsum, int n) {
    __shared__ int wsum[4];
    int t = threadIdx.x, b = blockIdx.x;
    int i0 = b * SCAN2_CHUNK + t * 8;
    int s = 0;
    #pragma unroll
    for (int k = 0; k < 8; ++k) { int i = i0 + k; if (i < n) s += in[i]; }
    #pragma unroll
    for (int off = 1; off < 64; off <<= 1) s += __shfl_xor(s, off);
    if ((t & 63) == 0) wsum[t >> 6] = s;
    __syncthreads();
    if (t == 0) bsum[b] = wsum[0] + wsum[1] + wsum[2] + wsum[3];
}

// ---------- scan phase 2: single-block scan of block sums (nb <= 512) ----------
__global__ void scan_phase2(const int* __restrict__ bsum, int* __restrict__ boff, int nb) {
    __shared__ int lds[512];
    int t = threadIdx.x;
    lds[t] = (t < nb) ? bsum[t] : 0;
    __syncthreads();
    for (int off = 1; off < 512; off <<= 1) {
        int v = (t >= off) ? lds[t - off] : 0;
        __syncthreads();
        lds[t] += v;
        __syncthreads();
    }
    if (t < nb) boff[t] = (t == 0) ? 0 : lds[t - 1];
}

// ---------- scan phase 3 (chunk 2048): write exclusive prefix ----------
__global__ void scan8_phase3(const int* __restrict__ in, const int* __restrict__ boff,
                             int* __restrict__ out, int n) {
    __shared__ int wexcl[4];
    int t = threadIdx.x, b = blockIdx.x;
    int lane = t & 63, w = t >> 6;
    int i0 = b * SCAN2_CHUNK + t * 8;
    int c[8];
    int s = 0;
    #pragma unroll
    for (int k = 0; k < 8; ++k) { int i = i0 + k; c[k] = (i < n) ? in[i] : 0; s += c[k]; }
    int incl = s;
    #pragma unroll
    for (int off = 1; off < 64; off <<= 1) {
        int u = __shfl_up(incl, off);
        if (lane >= off) incl += u;
    }
    if (lane == 63) wexcl[w] = incl;
    __syncthreads();
    int wbase = 0;
    for (int ww = 0; ww < w; ++ww) wbase += wexcl[ww];
    int run = incl - s + wbase + boff[b];
    #pragma unroll
    for (int k = 0; k < 8; ++k) {
        int i = i0 + k;
        if (i < n) { out[i] = run; run += c[k]; }
    }
}

// ---------- pass A3: scatter edges into bucket-partitioned staging (LDS cursors) ----------
__global__ __launch_bounds__(256) void bucket_scatter_kernel(
    const int* __restrict__ rows, const int* __restrict__ cols,
    const float* __restrict__ vals, const int* __restrict__ scanOut,
    int2* __restrict__ smeta, int nnz, int nbuck, int chunk) {
    __shared__ int cur[MAX_NBUCK];
    int t = threadIdx.x, blk = blockIdx.x;
    for (int u = t; u < nbuck; u += 256) cur[u] = scanOut[u * NBLK_A + blk];
    __syncthreads();
    int e0 = blk * chunk;
    int e1 = min(e0 + chunk, nnz);
    for (int e = e0 + t * 4; e < e1; e += 1024) {
        ix4 r4 = __builtin_nontemporal_load(reinterpret_cast<const ix4*>(rows + e));
        ix4 c4 = __builtin_nontemporal_load(reinterpret_cast<const ix4*>(cols + e));
        fv4 v4 = __builtin_nontemporal_load(reinterpret_cast<const fv4*>(vals + e));
        int p0 = atomicAdd(&cur[r4.x >> BUCKET_SHIFT], 1);
        smeta[p0] = make_int2(((r4.x & (BUCKET_ROWS - 1)) << COL_BITS) | c4.x, __float_as_int(v4.x));
        int p1 = atomicAdd(&cur[r4.y >> BUCKET_SHIFT], 1);
        smeta[p1] = make_int2(((r4.y & (BUCKET_ROWS - 1)) << COL_BITS) | c4.y, __float_as_int(v4.y));
        int p2 = atomicAdd(&cur[r4.z >> BUCKET_SHIFT], 1);
        smeta[p2] = make_int2(((r4.z & (BUCKET_ROWS - 1)) << COL_BITS) | c4.z, __float_as_int(v4.z));
        int p3 = atomicAdd(&cur[r4.w >> BUCKET_SHIFT], 1);
        smeta[p3] = make_int2(((r4.w & (BUCKET_ROWS - 1)) << COL_BITS) | c4.w, __float_as_int(v4.w));
    }
}

// ---------- pass B: per-bucket counting sort -> row_ptr + perm (LDS-staged) ----------
__global__ __launch_bounds__(256) void bucket_build_kernel(
    const int2* __restrict__ smeta, const int* __restrict__ scanOut,
    int2* __restrict__ perm, int* __restrict__ row_ptr,
    int nnz, int n_nodes, int nbuck) {
    __shared__ int hist[BUCKET_ROWS], excl[BUCKET_ROWS], cur[BUCKET_ROWS];
    __shared__ int wex[4];
    __shared__ int2 stage[STAGE_CAP];
    int t = threadIdx.x, b = blockIdx.x;
    int lane = t & 63, w = t >> 6;
    int ebeg = scanOut[b * NBLK_A];
    int eend = (b + 1 < nbuck) ? scanOut[(b + 1) * NBLK_A] : nnz;
    hist[t] = 0; hist[t + 256] = 0;
    __syncthreads();
    for (int e = ebeg + t; e < eend; e += 256)
        atomicAdd(&hist[smeta[e].x >> COL_BITS], 1);
    __syncthreads();
    int a = hist[2 * t], bcnt = hist[2 * t + 1];
    int s = a + bcnt;
    int incl = s;
    #pragma unroll
    for (int off = 1; off < 64; off <<= 1) {
        int u = __shfl_up(incl, off);
        if (lane >= off) incl += u;
    }
    if (lane == 63) wex[w] = incl;
    __syncthreads();
    int wbase = 0;
    for (int ww = 0; ww < w; ++ww) wbase += wex[ww];
    int es = wbase + incl - s;
    excl[2 * t] = es;
    excl[2 * t + 1] = es + a;
    cur[2 * t] = es;
    cur[2 * t + 1] = es + a;
    __syncthreads();
    int base_row = b << BUCKET_SHIFT;
    for (int r = t; r < BUCKET_ROWS; r += 256) {
        int gr = base_row + r;
        if (gr < n_nodes) row_ptr[gr] = ebeg + excl[r];
    }
    if (b == 0 && t == 0) row_ptr[n_nodes] = nnz;
    int nbe = eend - ebeg;
    if (nbe <= STAGE_CAP) {
        for (int e = ebeg + t; e < eend; e += 256) {
            int2 m = smeta[e];
            int l = m.x >> COL_BITS;
            int p = atomicAdd(&cur[l], 1);
            stage[p] = make_int2(m.x & ((1 << COL_BITS) - 1), m.y);
        }
        __syncthreads();
        for (int i = t; i < nbe; i += 256)
            perm[ebeg + i] = stage[i];
    } else {
        for (int e = ebeg + t; e < eend; e += 256) {
            int2 m = smeta[e];
            int l = m.x >> COL_BITS;
            int p = atomicAdd(&cur[l], 1);
            perm[ebeg + p] = make_int2(m.x & ((1 << COL_BITS) - 1), m.y);
        }
    }
}

// ---------- batch accumulator init (float4, from fp32 embeddings) ----------
__global__ void init_bacc_kernel(const float* __restrict__ ue, const float* __restrict__ ie,
                                 const int* __restrict__ uids, const int* __restrict__ iids,
                                 float* __restrict__ uacc, float* __restrict__ iacc, int batch) {
    int t = blockIdx.x * blockDim.x + threadIdx.x;
    if (t >= batch * 16) return;
    int b = t >> 4;
    int q = t & 15;
    const float4* ue4 = (const float4*)ue;
    const float4* ie4 = (const float4*)ie;
    ((float4*)uacc)[t] = ue4[(long)uids[b] * 16 + q];
    ((float4*)iacc)[t] = ie4[(long)iids[b] * 16 + q];
}

// ---------- mark nodes whose layer-2 output is actually consumed ----------
__global__ __launch_bounds__(256) void mark_needed_kernel(
    const int* __restrict__ row_ptr, const int2* __restrict__ perm,
    const int* __restrict__ uids, const int* __restrict__ iids,
    char* __restrict__ needed, int batch, int num_users) {
    int lane = threadIdx.x & 63;
    int w = (blockIdx.x * blockDim.x + threadIdx.x) >> 6;
    if (w >= 2 * batch) return;
    int row = (w < batch) ? uids[w] : num_users + iids[w - batch];
    if (lane == 0) needed[row] = 1;
    int start = row_ptr[row];
    int end   = row_ptr[row + 1];
    for (int e = start + lane; e < end; e += 64)
        needed[perm[e].x] = 1;
}

// ---------- fp16 CSR gather SpMM: one wave per row, 8 edge-slots x 8 dim-lanes ----------
// 24 edges per iteration (3 independent groups). Packed fp16 partial product
// (<=3 terms) flushed to fp32 per iteration. Optional needed[] filter.
__global__ __launch_bounds__(256) void spmm_csr_h_kernel(
    const int* __restrict__ row_ptr, const int2* __restrict__ perm,
    const _Float16* __restrict__ x, _Float16* __restrict__ y,
    const char* __restrict__ needed, int n_nodes) {
    int lane = threadIdx.x & 63;
    int row = (blockIdx.x * blockDim.x + threadIdx.x) >> 6;
    if (row >= n_nodes) return;
    if (needed && !needed[row]) return;
    int start = row_ptr[row];
    int end   = row_ptr[row + 1];
    int sub  = lane >> 3;    // edge slot 0..7
    unsigned dimb = ((unsigned)(lane & 7)) << 4;   // byte offset of half8 within row
    const char* xb = reinterpret_cast<const char*>(x);
    float accf[8];
    #pragma unroll
    for (int k = 0; k < 8; ++k) accf[k] = 0.f;
    for (int base = start; base < end; base += 24) {
        int e0 = base + sub;
        int e1 = e0 + 8;
        int e2 = e0 + 16;
        int2 p0 = (e0 < end) ? perm[e0] : make_int2(0, 0);
        int2 p1 = (e1 < end) ? perm[e1] : make_int2(0, 0);
        int2 p2 = (e2 < end) ? perm[e2] : make_int2(0, 0);
        _Float16 vh0 = (_Float16)__int_as_float(p0.y);
        _Float16 vh1 = (_Float16)__int_as_float(p1.y);
        _Float16 vh2 = (_Float16)__int_as_float(p2.y);
        h8v xv0 = *reinterpret_cast<const h8v*>(xb + ((((unsigned)p0.x) << 7) | dimb));
        h8v xv1 = *reinterpret_cast<const h8v*>(xb + ((((unsigned)p1.x) << 7) | dimb));
        h8v xv2 = *reinterpret_cast<const h8v*>(xb + ((((unsigned)p2.x) << 7) | dimb));
        h8v p = xv0 * vh0;           // packed fp16 math: 4x v_pk ops per line
        p += xv1 * vh1;
        p += xv2 * vh2;
        #pragma unroll
        for (int k = 0; k < 8; ++k) accf[k] += (float)p[k];
    }
    #pragma unroll
    for (int off = 8; off < 64; off <<= 1) {
        #pragma unroll
        for (int k = 0; k < 8; ++k) accf[k] += __shfl_xor(accf[k], off);
    }
    if (sub == 0) {
        h8v o;
        #pragma unroll
        for (int k = 0; k < 8; ++k) o[k] = (_Float16)accf[k];
        *reinterpret_cast<h8v*>(reinterpret_cast<char*>(y) + ((((unsigned)row) << 7) | dimb)) = o;
    }
}

// ---------- fused layer-3 batch SpMM + scoring (packed fp16 partials) ----------
__global__ __launch_bounds__(256) void spmm_batch_score_kernel(
    const int* __restrict__ row_ptr, const int2* __restrict__ perm,
    const _Float16* __restrict__ x,
    const int* __restrict__ uids, const int* __restrict__ iids,
    const float* __restrict__ uacc, const float* __restrict__ iacc,
    float* __restrict__ out, int batch, int num_users) {
    int lane = threadIdx.x & 63;
    int b = (blockIdx.x * blockDim.x + threadIdx.x) >> 6;
    if (b >= batch) return;
    int sub  = lane >> 3;
    int dimq = lane & 7;
    unsigned dimb = ((unsigned)dimq) << 4;
    const char* xb = reinterpret_cast<const char*>(x);
    float u3[8], i3[8];
    #pragma unroll
    for (int k = 0; k < 8; ++k) { u3[k] = 0.f; i3[k] = 0.f; }
    // --- u row ---
    {
        int row = uids[b];
        int start = row_ptr[row];
        int end   = row_ptr[row + 1];
        for (int base = start; base < end; base += 16) {
            int e0 = base + sub;
            int e1 = e0 + 8;
            int2 p0 = (e0 < end) ? perm[e0] : make_int2(0, 0);
            int2 p1 = (e1 < end) ? perm[e1] : make_int2(0, 0);
            _Float16 vh0 = (_Float16)__int_as_float(p0.y);
            _Float16 vh1 = (_Float16)__int_as_float(p1.y);
            h8v xv0 = *reinterpret_cast<const h8v*>(xb + ((((unsigned)p0.x) << 7) | dimb));
            h8v xv1 = *reinterpret_cast<const h8v*>(xb + ((((unsigned)p1.x) << 7) | dimb));
            h8v p = xv0 * vh0;
            p += xv1 * vh1;
            #pragma unroll
            for (int k = 0; k < 8; ++k) u3[k] += (float)p[k];
        }
    }
    // --- i row ---
    {
        int row = num_users + iids[b];
        int start = row_ptr[row];
        int end   = row_ptr[row + 1];
        for (int base = start; base < end; base += 16) {
            int e0 = base + sub;
            int e1 = e0 + 8;
            int2 p0 = (e0 < end) ? perm[e0] : make_int2(0, 0);
            int2 p1 = (e1 < end) ? perm[e1] : make_int2(0, 0);
            _Float16 vh0 = (_Float16)__int_as_float(p0.y);
            _Float16 vh1 = (_Float16)__int_as_float(p1.y);
            h8v xv0 = *reinterpret_cast<const h8v*>(xb + ((((unsigned)p0.x) << 7) | dimb));
            h8v xv1 = *reinterpret_cast<const h8v*>(xb + ((((unsigned)p1.x) << 7) | dimb));
            h8v p = xv0 * vh0;
            p += xv1 * vh1;
            #pragma unroll
            for (int k = 0; k < 8; ++k) i3[k] += (float)p[k];
        }
    }
    #pragma unroll
    for (int off = 8; off < 64; off <<= 1) {
        #pragma unroll
        for (int k = 0; k < 8; ++k) {
            u3[k] += __shfl_xor(u3[k], off);
            i3[k] += __shfl_xor(i3[k], off);
        }
    }
    const fx4* ua = reinterpret_cast<const fx4*>(uacc + (long)b * EMBED_DIM) + dimq * 2;
    const fx4* ia = reinterpret_cast<const fx4*>(iacc + (long)b * EMBED_DIM) + dimq * 2;
    fx4 ulo = ua[0], uhi = ua[1];
    fx4 ilo = ia[0], ihi = ia[1];
    float s = 0.f;
    s += (ulo.x + u3[0]) * (ilo.x + i3[0]);
    s += (ulo.y + u3[1]) * (ilo.y + i3[1]);
    s += (ulo.z + u3[2]) * (ilo.z + i3[2]);
    s += (ulo.w + u3[3]) * (ilo.w + i3[3]);
    s += (uhi.x + u3[4]) * (ihi.x + i3[4]);
    s += (uhi.y + u3[5]) * (ihi.y + i3[5]);
    s += (uhi.z + u3[6]) * (ihi.z + i3[6]);
    s += (uhi.w + u3[7]) * (ihi.w + i3[7]);
    #pragma unroll
    for (int off = 1; off < 8; off <<= 1) s += __shfl_xor(s, off);
    if (lane == 0) out[b] = s * (1.0f / 16.0f);  // (acc/4)·(acc/4)
}

// ---------- per-layer batch accumulate: fp16 y -> fp32 acc ----------
__global__ void bacc_add_h_kernel(const _Float16* __restrict__ y,
                                  const int* __restrict__ uids, const int* __restrict__ iids,
                                  float* __restrict__ uacc, float* __restrict__ iacc,
                                  int batch, int num_users) {
    int t = blockIdx.x * blockDim.x + threadIdx.x;
    if (t >= batch * 8) return;
    int b = t >> 3;
    int q = t & 7;
    const h8v* y8 = (const h8v*)y;
    h8v u = y8[(long)uids[b] * 8 + q];
    h8v v = y8[((long)num_users + iids[b]) * 8 + q];
    float4* ua = (float4*)uacc + (long)b * 16 + q * 2;
    float4* ia = (float4*)iacc + (long)b * 16 + q * 2;
    float4 a0 = ua[0], a1 = ua[1];
    a0.x += (float)u[0]; a0.y += (float)u[1]; a0.z += (float)u[2]; a0.w += (float)u[3];
    a1.x += (float)u[4]; a1.y += (float)u[5]; a1.z += (float)u[6]; a1.w += (float)u[7];
    ua[0] = a0; ua[1] = a1;
    float4 c0 = ia[0], c1 = ia[1];
    c0.x += (float)v[0]; c0.y += (float)v[1]; c0.z += (float)v[2]; c0.w += (float)v[3];
    c1.x += (float)v[4]; c1.y += (float)v[5]; c1.z += (float)v[6]; c1.w += (float)v[7];
    ia[0] = c0; ia[1] = c1;
}

extern "C" void kernel_launch(void* const* d_in, const int* in_sizes, int n_in,
                              void* d_out, int out_size, void* d_ws, size_t ws_size,
                              hipStream_t stream) {
    const float* user_emb = (const float*)d_in[0];
    const float* item_emb = (const float*)d_in[1];
    const int*   adj_rows = (const int*)d_in[2];
    const int*   adj_cols = (const int*)d_in[3];
    const float* adj_vals = (const float*)d_in[4];
    const int*   user_ids = (const int*)d_in[5];
    const int*   item_ids = (const int*)d_in[6];
    float* out = (float*)d_out;

    const int num_users = in_sizes[0] / EMBED_DIM;   // 200000
    const int num_items = in_sizes[1] / EMBED_DIM;   // 100000
    const int n_nodes   = num_users + num_items;     // 300000
    const int nnz       = in_sizes[2];               // 6000000
    const int batch     = in_sizes[5];               // 16384

    const long node_elems = (long)n_nodes * EMBED_DIM;    // 19.2M elems
    const long bacc_elems = (long)batch * EMBED_DIM;      // 1.05M floats

    const int nbuck = (n_nodes + BUCKET_ROWS - 1) >> BUCKET_SHIFT;   // 586
    const int nscan = nbuck * NBLK_A;                                // 150016
    const int nscan_blocks = (nscan + SCAN2_CHUNK - 1) / SCAN2_CHUNK; // 74

    // ---- workspace layout ----
    char* wp = (char*)d_ws;
    _Float16* xh   = (_Float16*)wp;      wp += node_elems * sizeof(_Float16);
    _Float16* bufA = (_Float16*)wp;      wp += node_elems * sizeof(_Float16);
    _Float16* bufB = (_Float16*)wp;      wp += node_elems * sizeof(_Float16);
    float* uacc = (float*)wp;            wp += bacc_elems * sizeof(float);
    float* iacc = (float*)wp;            wp += bacc_elems * sizeof(float);
    int*   row_ptr = (int*)wp;           wp += (size_t)(n_nodes + 4) * sizeof(int);
    int*   bsum    = (int*)wp;           wp += 512 * sizeof(int);
    int*   boff    = (int*)wp;           wp += 512 * sizeof(int);
    int*   blockCounts = (int*)wp;       wp += (size_t)nscan * sizeof(int);
    int*   scanOut     = (int*)wp;       wp += (size_t)nscan * sizeof(int);
    char*  needed      = wp;             wp += (size_t)n_nodes;
    wp = (char*)(((uintptr_t)wp + 15) & ~(uintptr_t)15);
    int2*  perm    = (int2*)wp;          wp += (size_t)nnz * sizeof(int2);

    // smeta staging (48 MB) overlays bufA+bufB (76.8 MB contiguous): both are
    // first written by spmm layers, which run after bucket_build consumes smeta.
    int2* smeta = (int2*)bufA;

    const int chunkA = (((nnz + NBLK_A - 1) / NBLK_A) + 1023) & ~1023;   // 24576

    // ---- radix CSR build (no device atomics) ----
    bucket_count_kernel<<<NBLK_A, 256, 0, stream>>>(adj_rows, blockCounts, nnz, nbuck, chunkA);
    scan8_phase1<<<nscan_blocks, 256, 0, stream>>>(blockCounts, bsum, nscan);
    scan_phase2<<<1, 512, 0, stream>>>(bsum, boff, nscan_blocks);
    scan8_phase3<<<nscan_blocks, 256, 0, stream>>>(blockCounts, boff, scanOut, nscan);
    bucket_scatter_kernel<<<NBLK_A, 256, 0, stream>>>(adj_rows, adj_cols, adj_vals,
                                                      scanOut, smeta, nnz, nbuck, chunkA);
    bucket_build_kernel<<<nbuck, 256, 0, stream>>>(smeta, scanOut, perm,
                                                   row_ptr, nnz, n_nodes, nbuck);

    // ---- convert x0 to fp16 ----
    convert_x_kernel<<<2048, 256, 0, stream>>>(user_emb, item_emb, xh,
                                               num_users * EMBED_DIM, (int)node_elems);

    // ---- batch accumulator init (layer-0 term, fp32) ----
    {
        int blocks = (batch * 16 + 255) / 256;
        init_bacc_kernel<<<blocks, 256, 0, stream>>>(user_emb, item_emb, user_ids, item_ids,
                                                     uacc, iacc, batch);
    }

    // ---- needed-set for layer 2 (batch rows + their neighbors) ----
    hipMemsetAsync(needed, 0, (size_t)n_nodes, stream);
    {
        int waves = 2 * batch;
        int blocks = (waves * 64 + 255) / 256;
        mark_needed_kernel<<<blocks, 256, 0, stream>>>(row_ptr, perm, user_ids, item_ids,
                                                       needed, batch, num_users);
    }

    const int spmm_blocks = ((n_nodes * 64) + 255) / 256;   // one wave per row
    const int bblocks = (batch * 8 + 255) / 256;

    // ---- layer 1: xh -> bufA (all rows) ----
    spmm_csr_h_kernel<<<spmm_blocks, 256, 0, stream>>>(row_ptr, perm, xh, bufA,
                                                       nullptr, n_nodes);
    bacc_add_h_kernel<<<bblocks, 256, 0, stream>>>(bufA, user_ids, item_ids,
                                                   uacc, iacc, batch, num_users);

    // ---- layer 2: bufA -> bufB (needed rows only) ----
    spmm_csr_h_kernel<<<spmm_blocks, 256, 0, stream>>>(row_ptr, perm, bufA, bufB,
                                                       needed, n_nodes);
    bacc_add_h_kernel<<<bblocks, 256, 0, stream>>>(bufB, user_ids, item_ids,
                                                   uacc, iacc, batch, num_users);

    // ---- layer 3 (batch-restricted) fused with scoring ----
    {
        int blocks = (batch * 64 + 255) / 256;       // one wave per batch element
        spmm_batch_score_kernel<<<blocks, 256, 0, stream>>>(row_ptr, perm, bufB,
                                                            user_ids, item_ids,
                                                            uacc, iacc, out,
                                                            batch, num_users);
    }
}

// Round 14
// 482.499 us; speedup vs baseline: 1.0736x; 1.0133x over previous
//
#include <hip/hip_runtime.h>

#define EMBED_DIM 64
#define NBLK_A 256            // blocks in bucket count/scatter passes
#define BUCKET_SHIFT 9        // 512 rows per bucket
#define BUCKET_ROWS 512
#define MAX_NBUCK 640
#define SCAN2_CHUNK 2048      // 256 threads x 8
#define COL_BITS 19           // col < 2^19; meta = (localrow << 19) | col
#define STAGE_CAP 15360       // LDS staging capacity (120 KB); bucket avg 10.2K, +50 sigma

typedef float fx4 __attribute__((ext_vector_type(4)));
typedef int   ix4 __attribute__((ext_vector_type(4)));
typedef float fv4 __attribute__((ext_vector_type(4)));
typedef _Float16 h8v __attribute__((ext_vector_type(8)));

// ---------- convert concat(user_emb, item_emb) fp32 -> fp16 ----------
__global__ void convert_x_kernel(const float* __restrict__ ue, const float* __restrict__ ie,
                                 _Float16* __restrict__ xh, int nu_elems, int total) {
    int i = blockIdx.x * blockDim.x + threadIdx.x;   // index in units of 8 elems
    int stride = gridDim.x * blockDim.x;
    int n8 = total >> 3;
    int nu8 = nu_elems >> 3;
    for (; i < n8; i += stride) {
        const float4* src = (i < nu8) ? (const float4*)(ue) + 2 * i
                                      : (const float4*)(ie) + 2 * (i - nu8);
        float4 lo = src[0];
        float4 hi = src[1];
        h8v o;
        o[0] = (_Float16)lo.x; o[1] = (_Float16)lo.y;
        o[2] = (_Float16)lo.z; o[3] = (_Float16)lo.w;
        o[4] = (_Float16)hi.x; o[5] = (_Float16)hi.y;
        o[6] = (_Float16)hi.z; o[7] = (_Float16)hi.w;
        reinterpret_cast<h8v*>(xh)[i] = o;
    }
}

// ---------- pass A1: per-block bucket histogram (LDS), bucket-major dump ----------
__global__ __launch_bounds__(256) void bucket_count_kernel(
    const int* __restrict__ rows, int* __restrict__ blockCounts,
    int nnz, int nbuck, int chunk) {
    __shared__ int hist[MAX_NBUCK];
    int t = threadIdx.x, blk = blockIdx.x;
    for (int i = t; i < nbuck; i += 256) hist[i] = 0;
    __syncthreads();
    int e0 = blk * chunk;
    int e1 = min(e0 + chunk, nnz);
    for (int e = e0 + t * 4; e < e1; e += 1024) {
        ix4 r4 = __builtin_nontemporal_load(reinterpret_cast<const ix4*>(rows + e));
        atomicAdd(&hist[r4.x >> BUCKET_SHIFT], 1);
        atomicAdd(&hist[r4.y >> BUCKET_SHIFT], 1);
        atomicAdd(&hist[r4.z >> BUCKET_SHIFT], 1);
        atomicAdd(&hist[r4.w >> BUCKET_SHIFT], 1);
    }
    __syncthreads();
    for (int u = t; u < nbuck; u += 256)
        blockCounts[u * NBLK_A + blk] = hist[u];
}

// ---------- scan phase 1 (chunk 2048): per-block sums ----------
__global__ void scan8_phase1(const int* __restrict__ in, int* __restrict__ bsum, int n) {
    __shared__ int wsum[4];
    int t = threadIdx.x, b = blockIdx.x;
    int i0 = b * SCAN2_CHUNK + t * 8;
    int s = 0;
    #pragma unroll
    for (int k = 0; k < 8; ++k) { int i = i0 + k; if (i < n) s += in[i]; }
    #pragma unroll
    for (int off = 1; off < 64; off <<= 1) s += __shfl_xor(s, off);
    if ((t & 63) == 0) wsum[t >> 6] = s;
    __syncthreads();
    if (t == 0) bsum[b] = wsum[0] + wsum[1] + wsum[2] + wsum[3];
}

// ---------- scan phase 2: single-block scan of block sums (nb <= 512) ----------
__global__ void scan_phase2(const int* __restrict__ bsum, int* __restrict__ boff, int nb) {
    __shared__ int lds[512];
    int t = threadIdx.x;
    lds[t] = (t < nb) ? bsum[t] : 0;
    __syncthreads();
    for (int off = 1; off < 512; off <<= 1) {
        int v = (t >= off) ? lds[t - off] : 0;
        __syncthreads();
        lds[t] += v;
        __syncthreads();
    }
    if (t < nb) boff[t] = (t == 0) ? 0 : lds[t - 1];
}

// ---------- scan phase 3 (chunk 2048): write exclusive prefix ----------
__global__ void scan8_phase3(const int* __restrict__ in, const int* __restrict__ boff,
                             int* __restrict__ out, int n) {
    __shared__ int wexcl[4];
    int t = threadIdx.x, b = blockIdx.x;
    int lane = t & 63, w = t >> 6;
    int i0 = b * SCAN2_CHUNK + t * 8;
    int c[8];
    int s = 0;
    #pragma unroll
    for (int k = 0; k < 8; ++k) { int i = i0 + k; c[k] = (i < n) ? in[i] : 0; s += c[k]; }
    int incl = s;
    #pragma unroll
    for (int off = 1; off < 64; off <<= 1) {
        int u = __shfl_up(incl, off);
        if (lane >= off) incl += u;
    }
    if (lane == 63) wexcl[w] = incl;
    __syncthreads();
    int wbase = 0;
    for (int ww = 0; ww < w; ++ww) wbase += wexcl[ww];
    int run = incl - s + wbase + boff[b];
    #pragma unroll
    for (int k = 0; k < 8; ++k) {
        int i = i0 + k;
        if (i < n) { out[i] = run; run += c[k]; }
    }
}

// ---------- pass A3: scatter edges into bucket-partitioned staging (LDS cursors) ----------
__global__ __launch_bounds__(256) void bucket_scatter_kernel(
    const int* __restrict__ rows, const int* __restrict__ cols,
    const float* __restrict__ vals, const int* __restrict__ scanOut,
    int2* __restrict__ smeta, int nnz, int nbuck, int chunk) {
    __shared__ int cur[MAX_NBUCK];
    int t = threadIdx.x, blk = blockIdx.x;
    for (int u = t; u < nbuck; u += 256) cur[u] = scanOut[u * NBLK_A + blk];
    __syncthreads();
    int e0 = blk * chunk;
    int e1 = min(e0 + chunk, nnz);
    for (int e = e0 + t * 4; e < e1; e += 1024) {
        ix4 r4 = __builtin_nontemporal_load(reinterpret_cast<const ix4*>(rows + e));
        ix4 c4 = __builtin_nontemporal_load(reinterpret_cast<const ix4*>(cols + e));
        fv4 v4 = __builtin_nontemporal_load(reinterpret_cast<const fv4*>(vals + e));
        int p0 = atomicAdd(&cur[r4.x >> BUCKET_SHIFT], 1);
        smeta[p0] = make_int2(((r4.x & (BUCKET_ROWS - 1)) << COL_BITS) | c4.x, __float_as_int(v4.x));
        int p1 = atomicAdd(&cur[r4.y >> BUCKET_SHIFT], 1);
        smeta[p1] = make_int2(((r4.y & (BUCKET_ROWS - 1)) << COL_BITS) | c4.y, __float_as_int(v4.y));
        int p2 = atomicAdd(&cur[r4.z >> BUCKET_SHIFT], 1);
        smeta[p2] = make_int2(((r4.z & (BUCKET_ROWS - 1)) << COL_BITS) | c4.z, __float_as_int(v4.z));
        int p3 = atomicAdd(&cur[r4.w >> BUCKET_SHIFT], 1);
        smeta[p3] = make_int2(((r4.w & (BUCKET_ROWS - 1)) << COL_BITS) | c4.w, __float_as_int(v4.w));
    }
}

// ---------- pass B: per-bucket counting sort -> row_ptr + perm ----------
// Single global read: bucket's smeta staged raw in LDS (histogram during load),
// then placed into perm from LDS. Fallback to double-read if bucket overflows.
__global__ __launch_bounds__(256) void bucket_build_kernel(
    const int2* __restrict__ smeta, const int* __restrict__ scanOut,
    int2* __restrict__ perm, int* __restrict__ row_ptr,
    int nnz, int n_nodes, int nbuck) {
    __shared__ int hist[BUCKET_ROWS], excl[BUCKET_ROWS], cur[BUCKET_ROWS];
    __shared__ int wex[4];
    __shared__ int2 stage[STAGE_CAP];
    int t = threadIdx.x, b = blockIdx.x;
    int lane = t & 63, w = t >> 6;
    int ebeg = scanOut[b * NBLK_A];
    int eend = (b + 1 < nbuck) ? scanOut[(b + 1) * NBLK_A] : nnz;
    int nbe = eend - ebeg;
    hist[t] = 0; hist[t + 256] = 0;
    __syncthreads();
    bool fit = (nbe <= STAGE_CAP);
    if (fit) {
        for (int i = t; i < nbe; i += 256) {
            int2 m = smeta[ebeg + i];
            stage[i] = m;
            atomicAdd(&hist[m.x >> COL_BITS], 1);
        }
    } else {
        for (int e = ebeg + t; e < eend; e += 256)
            atomicAdd(&hist[smeta[e].x >> COL_BITS], 1);
    }
    __syncthreads();
    // 512-bin exclusive scan with 256 threads (2 bins each)
    int a = hist[2 * t], bcnt = hist[2 * t + 1];
    int s = a + bcnt;
    int incl = s;
    #pragma unroll
    for (int off = 1; off < 64; off <<= 1) {
        int u = __shfl_up(incl, off);
        if (lane >= off) incl += u;
    }
    if (lane == 63) wex[w] = incl;
    __syncthreads();
    int wbase = 0;
    for (int ww = 0; ww < w; ++ww) wbase += wex[ww];
    int es = wbase + incl - s;
    excl[2 * t] = es;
    excl[2 * t + 1] = es + a;
    cur[2 * t] = es;
    cur[2 * t + 1] = es + a;
    __syncthreads();
    // write row_ptr for this bucket's rows
    int base_row = b << BUCKET_SHIFT;
    for (int r = t; r < BUCKET_ROWS; r += 256) {
        int gr = base_row + r;
        if (gr < n_nodes) row_ptr[gr] = ebeg + excl[r];
    }
    if (b == 0 && t == 0) row_ptr[n_nodes] = nnz;
    if (fit) {
        for (int i = t; i < nbe; i += 256) {
            int2 m = stage[i];
            int l = m.x >> COL_BITS;
            int p = atomicAdd(&cur[l], 1);
            perm[ebeg + p] = make_int2(m.x & ((1 << COL_BITS) - 1), m.y);
        }
    } else {
        for (int e = ebeg + t; e < eend; e += 256) {
            int2 m = smeta[e];
            int l = m.x >> COL_BITS;
            int p = atomicAdd(&cur[l], 1);
            perm[ebeg + p] = make_int2(m.x & ((1 << COL_BITS) - 1), m.y);
        }
    }
}

// ---------- batch accumulator init (float4, from fp32 embeddings) ----------
__global__ void init_bacc_kernel(const float* __restrict__ ue, const float* __restrict__ ie,
                                 const int* __restrict__ uids, const int* __restrict__ iids,
                                 float* __restrict__ uacc, float* __restrict__ iacc, int batch) {
    int t = blockIdx.x * blockDim.x + threadIdx.x;
    if (t >= batch * 16) return;
    int b = t >> 4;
    int q = t & 15;
    const float4* ue4 = (const float4*)ue;
    const float4* ie4 = (const float4*)ie;
    ((float4*)uacc)[t] = ue4[(long)uids[b] * 16 + q];
    ((float4*)iacc)[t] = ie4[(long)iids[b] * 16 + q];
}

// ---------- fp16 CSR gather SpMM: one wave per row, 8 edge-slots x 8 dim-lanes ----------
// 24 edges per iteration (3 independent groups). Packed fp16 partial product
// (<=3 terms) flushed to fp32 per iteration.
__global__ __launch_bounds__(256) void spmm_csr_h_kernel(
    const int* __restrict__ row_ptr, const int2* __restrict__ perm,
    const _Float16* __restrict__ x, _Float16* __restrict__ y, int n_nodes) {
    int lane = threadIdx.x & 63;
    int row = (blockIdx.x * blockDim.x + threadIdx.x) >> 6;
    if (row >= n_nodes) return;
    int start = row_ptr[row];
    int end   = row_ptr[row + 1];
    int sub  = lane >> 3;    // edge slot 0..7
    unsigned dimb = ((unsigned)(lane & 7)) << 4;   // byte offset of half8 within row
    const char* xb = reinterpret_cast<const char*>(x);
    float accf[8];
    #pragma unroll
    for (int k = 0; k < 8; ++k) accf[k] = 0.f;
    for (int base = start; base < end; base += 24) {
        int e0 = base + sub;
        int e1 = e0 + 8;
        int e2 = e0 + 16;
        int2 p0 = (e0 < end) ? perm[e0] : make_int2(0, 0);
        int2 p1 = (e1 < end) ? perm[e1] : make_int2(0, 0);
        int2 p2 = (e2 < end) ? perm[e2] : make_int2(0, 0);
        _Float16 vh0 = (_Float16)__int_as_float(p0.y);
        _Float16 vh1 = (_Float16)__int_as_float(p1.y);
        _Float16 vh2 = (_Float16)__int_as_float(p2.y);
        h8v xv0 = *reinterpret_cast<const h8v*>(xb + ((((unsigned)p0.x) << 7) | dimb));
        h8v xv1 = *reinterpret_cast<const h8v*>(xb + ((((unsigned)p1.x) << 7) | dimb));
        h8v xv2 = *reinterpret_cast<const h8v*>(xb + ((((unsigned)p2.x) << 7) | dimb));
        h8v p = xv0 * vh0;           // packed fp16 math
        p += xv1 * vh1;
        p += xv2 * vh2;
        #pragma unroll
        for (int k = 0; k < 8; ++k) accf[k] += (float)p[k];
    }
    #pragma unroll
    for (int off = 8; off < 64; off <<= 1) {
        #pragma unroll
        for (int k = 0; k < 8; ++k) accf[k] += __shfl_xor(accf[k], off);
    }
    if (sub == 0) {
        h8v o;
        #pragma unroll
        for (int k = 0; k < 8; ++k) o[k] = (_Float16)accf[k];
        *reinterpret_cast<h8v*>(reinterpret_cast<char*>(y) + ((((unsigned)row) << 7) | dimb)) = o;
    }
}

// ---------- fused layer-3 batch SpMM + scoring (packed fp16 partials) ----------
__global__ __launch_bounds__(256) void spmm_batch_score_kernel(
    const int* __restrict__ row_ptr, const int2* __restrict__ perm,
    const _Float16* __restrict__ x,
    const int* __restrict__ uids, const int* __restrict__ iids,
    const float* __restrict__ uacc, const float* __restrict__ iacc,
    float* __restrict__ out, int batch, int num_users) {
    int lane = threadIdx.x & 63;
    int b = (blockIdx.x * blockDim.x + threadIdx.x) >> 6;
    if (b >= batch) return;
    int sub  = lane >> 3;
    int dimq = lane & 7;
    unsigned dimb = ((unsigned)dimq) << 4;
    const char* xb = reinterpret_cast<const char*>(x);
    float u3[8], i3[8];
    #pragma unroll
    for (int k = 0; k < 8; ++k) { u3[k] = 0.f; i3[k] = 0.f; }
    // --- u row ---
    {
        int row = uids[b];
        int start = row_ptr[row];
        int end   = row_ptr[row + 1];
        for (int base = start; base < end; base += 16) {
            int e0 = base + sub;
            int e1 = e0 + 8;
            int2 p0 = (e0 < end) ? perm[e0] : make_int2(0, 0);
            int2 p1 = (e1 < end) ? perm[e1] : make_int2(0, 0);
            _Float16 vh0 = (_Float16)__int_as_float(p0.y);
            _Float16 vh1 = (_Float16)__int_as_float(p1.y);
            h8v xv0 = *reinterpret_cast<const h8v*>(xb + ((((unsigned)p0.x) << 7) | dimb));
            h8v xv1 = *reinterpret_cast<const h8v*>(xb + ((((unsigned)p1.x) << 7) | dimb));
            h8v p = xv0 * vh0;
            p += xv1 * vh1;
            #pragma unroll
            for (int k = 0; k < 8; ++k) u3[k] += (float)p[k];
        }
    }
    // --- i row ---
    {
        int row = num_users + iids[b];
        int start = row_ptr[row];
        int end   = row_ptr[row + 1];
        for (int base = start; base < end; base += 16) {
            int e0 = base + sub;
            int e1 = e0 + 8;
            int2 p0 = (e0 < end) ? perm[e0] : make_int2(0, 0);
            int2 p1 = (e1 < end) ? perm[e1] : make_int2(0, 0);
            _Float16 vh0 = (_Float16)__int_as_float(p0.y);
            _Float16 vh1 = (_Float16)__int_as_float(p1.y);
            h8v xv0 = *reinterpret_cast<const h8v*>(xb + ((((unsigned)p0.x) << 7) | dimb));
            h8v xv1 = *reinterpret_cast<const h8v*>(xb + ((((unsigned)p1.x) << 7) | dimb));
            h8v p = xv0 * vh0;
            p += xv1 * vh1;
            #pragma unroll
            for (int k = 0; k < 8; ++k) i3[k] += (float)p[k];
        }
    }
    #pragma unroll
    for (int off = 8; off < 64; off <<= 1) {
        #pragma unroll
        for (int k = 0; k < 8; ++k) {
            u3[k] += __shfl_xor(u3[k], off);
            i3[k] += __shfl_xor(i3[k], off);
        }
    }
    const fx4* ua = reinterpret_cast<const fx4*>(uacc + (long)b * EMBED_DIM) + dimq * 2;
    const fx4* ia = reinterpret_cast<const fx4*>(iacc + (long)b * EMBED_DIM) + dimq * 2;
    fx4 ulo = ua[0], uhi = ua[1];
    fx4 ilo = ia[0], ihi = ia[1];
    float s = 0.f;
    s += (ulo.x + u3[0]) * (ilo.x + i3[0]);
    s += (ulo.y + u3[1]) * (ilo.y + i3[1]);
    s += (ulo.z + u3[2]) * (ilo.z + i3[2]);
    s += (ulo.w + u3[3]) * (ilo.w + i3[3]);
    s += (uhi.x + u3[4]) * (ihi.x + i3[4]);
    s += (uhi.y + u3[5]) * (ihi.y + i3[5]);
    s += (uhi.z + u3[6]) * (ihi.z + i3[6]);
    s += (uhi.w + u3[7]) * (ihi.w + i3[7]);
    #pragma unroll
    for (int off = 1; off < 8; off <<= 1) s += __shfl_xor(s, off);
    if (lane == 0) out[b] = s * (1.0f / 16.0f);  // (acc/4)·(acc/4)
}

// ---------- per-layer batch accumulate: fp16 y -> fp32 acc ----------
__global__ void bacc_add_h_kernel(const _Float16* __restrict__ y,
                                  const int* __restrict__ uids, const int* __restrict__ iids,
                                  float* __restrict__ uacc, float* __restrict__ iacc,
                                  int batch, int num_users) {
    int t = blockIdx.x * blockDim.x + threadIdx.x;
    if (t >= batch * 8) return;
    int b = t >> 3;
    int q = t & 7;
    const h8v* y8 = (const h8v*)y;
    h8v u = y8[(long)uids[b] * 8 + q];
    h8v v = y8[((long)num_users + iids[b]) * 8 + q];
    float4* ua = (float4*)uacc + (long)b * 16 + q * 2;
    float4* ia = (float4*)iacc + (long)b * 16 + q * 2;
    float4 a0 = ua[0], a1 = ua[1];
    a0.x += (float)u[0]; a0.y += (float)u[1]; a0.z += (float)u[2]; a0.w += (float)u[3];
    a1.x += (float)u[4]; a1.y += (float)u[5]; a1.z += (float)u[6]; a1.w += (float)u[7];
    ua[0] = a0; ua[1] = a1;
    float4 c0 = ia[0], c1 = ia[1];
    c0.x += (float)v[0]; c0.y += (float)v[1]; c0.z += (float)v[2]; c0.w += (float)v[3];
    c1.x += (float)v[4]; c1.y += (float)v[5]; c1.z += (float)v[6]; c1.w += (float)v[7];
    ia[0] = c0; ia[1] = c1;
}

extern "C" void kernel_launch(void* const* d_in, const int* in_sizes, int n_in,
                              void* d_out, int out_size, void* d_ws, size_t ws_size,
                              hipStream_t stream) {
    const float* user_emb = (const float*)d_in[0];
    const float* item_emb = (const float*)d_in[1];
    const int*   adj_rows = (const int*)d_in[2];
    const int*   adj_cols = (const int*)d_in[3];
    const float* adj_vals = (const float*)d_in[4];
    const int*   user_ids = (const int*)d_in[5];
    const int*   item_ids = (const int*)d_in[6];
    float* out = (float*)d_out;

    const int num_users = in_sizes[0] / EMBED_DIM;   // 200000
    const int num_items = in_sizes[1] / EMBED_DIM;   // 100000
    const int n_nodes   = num_users + num_items;     // 300000
    const int nnz       = in_sizes[2];               // 6000000
    const int batch     = in_sizes[5];               // 16384

    const long node_elems = (long)n_nodes * EMBED_DIM;    // 19.2M elems
    const long bacc_elems = (long)batch * EMBED_DIM;      // 1.05M floats

    const int nbuck = (n_nodes + BUCKET_ROWS - 1) >> BUCKET_SHIFT;   // 586
    const int nscan = nbuck * NBLK_A;                                // 150016
    const int nscan_blocks = (nscan + SCAN2_CHUNK - 1) / SCAN2_CHUNK; // 74

    // ---- workspace layout ----
    char* wp = (char*)d_ws;
    _Float16* xh   = (_Float16*)wp;      wp += node_elems * sizeof(_Float16);
    _Float16* bufA = (_Float16*)wp;      wp += node_elems * sizeof(_Float16);
    _Float16* bufB = (_Float16*)wp;      wp += node_elems * sizeof(_Float16);
    float* uacc = (float*)wp;            wp += bacc_elems * sizeof(float);
    float* iacc = (float*)wp;            wp += bacc_elems * sizeof(float);
    int*   row_ptr = (int*)wp;           wp += (size_t)(n_nodes + 4) * sizeof(int);
    int*   bsum    = (int*)wp;           wp += 512 * sizeof(int);
    int*   boff    = (int*)wp;           wp += 512 * sizeof(int);
    int*   blockCounts = (int*)wp;       wp += (size_t)nscan * sizeof(int);
    int*   scanOut     = (int*)wp;       wp += (size_t)nscan * sizeof(int);
    wp = (char*)(((uintptr_t)wp + 15) & ~(uintptr_t)15);
    int2*  perm    = (int2*)wp;          wp += (size_t)nnz * sizeof(int2);

    // smeta staging (48 MB) overlays bufA+bufB (76.8 MB contiguous): both are
    // first written by spmm layers, which run after bucket_build consumes smeta.
    int2* smeta = (int2*)bufA;

    const int chunkA = (((nnz + NBLK_A - 1) / NBLK_A) + 1023) & ~1023;   // 24576

    // ---- radix CSR build (no device atomics) ----
    bucket_count_kernel<<<NBLK_A, 256, 0, stream>>>(adj_rows, blockCounts, nnz, nbuck, chunkA);
    scan8_phase1<<<nscan_blocks, 256, 0, stream>>>(blockCounts, bsum, nscan);
    scan_phase2<<<1, 512, 0, stream>>>(bsum, boff, nscan_blocks);
    scan8_phase3<<<nscan_blocks, 256, 0, stream>>>(blockCounts, boff, scanOut, nscan);
    bucket_scatter_kernel<<<NBLK_A, 256, 0, stream>>>(adj_rows, adj_cols, adj_vals,
                                                      scanOut, smeta, nnz, nbuck, chunkA);
    bucket_build_kernel<<<nbuck, 256, 0, stream>>>(smeta, scanOut, perm,
                                                   row_ptr, nnz, n_nodes, nbuck);

    // ---- convert x0 to fp16 ----
    convert_x_kernel<<<2048, 256, 0, stream>>>(user_emb, item_emb, xh,
                                               num_users * EMBED_DIM, (int)node_elems);

    // ---- batch accumulator init (layer-0 term, fp32) ----
    {
        int blocks = (batch * 16 + 255) / 256;
        init_bacc_kernel<<<blocks, 256, 0, stream>>>(user_emb, item_emb, user_ids, item_ids,
                                                     uacc, iacc, batch);
    }

    const int spmm_blocks = ((n_nodes * 64) + 255) / 256;   // one wave per row
    const int bblocks = (batch * 8 + 255) / 256;

    // ---- layer 1: xh -> bufA ----
    spmm_csr_h_kernel<<<spmm_blocks, 256, 0, stream>>>(row_ptr, perm, xh, bufA, n_nodes);
    bacc_add_h_kernel<<<bblocks, 256, 0, stream>>>(bufA, user_ids, item_ids,
                                                   uacc, iacc, batch, num_users);

    // ---- layer 2: bufA -> bufB ----
    spmm_csr_h_kernel<<<spmm_blocks, 256, 0, stream>>>(row_ptr, perm, bufA, bufB, n_nodes);
    bacc_add_h_kernel<<<bblocks, 256, 0, stream>>>(bufB, user_ids, item_ids,
                                                   uacc, iacc, batch, num_users);

    // ---- layer 3 (batch-restricted) fused with scoring ----
    {
        int blocks = (batch * 64 + 255) / 256;       // one wave per batch element
        spmm_batch_score_kernel<<<blocks, 256, 0, stream>>>(row_ptr, perm, bufB,
                                                            user_ids, item_ids,
                                                            uacc, iacc, out,
                                                            batch, num_users);
    }
}

// Round 15
// 469.091 us; speedup vs baseline: 1.1043x; 1.0286x over previous
//
#include <hip/hip_runtime.h>

#define EMBED_DIM 64
#define NBLK_A 256            // blocks in bucket count/scatter passes
#define BUCKET_SHIFT 9        // 512 rows per bucket
#define BUCKET_ROWS 512
#define MAX_NBUCK 640
#define SCAN2_CHUNK 2048      // 256 threads x 8
#define COL_BITS 19           // col < 2^19; meta = (localrow << 19) | col
#define STAGE_CAP 15360       // LDS staging capacity (120 KB); bucket avg 10.2K, +50 sigma

typedef float fx4 __attribute__((ext_vector_type(4)));
typedef int   ix4 __attribute__((ext_vector_type(4)));
typedef float fv4 __attribute__((ext_vector_type(4)));
typedef _Float16 h8v __attribute__((ext_vector_type(8)));

// ---------- convert concat(user_emb, item_emb) fp32 -> fp16 ----------
__global__ void convert_x_kernel(const float* __restrict__ ue, const float* __restrict__ ie,
                                 _Float16* __restrict__ xh, int nu_elems, int total) {
    int i = blockIdx.x * blockDim.x + threadIdx.x;   // index in units of 8 elems
    int stride = gridDim.x * blockDim.x;
    int n8 = total >> 3;
    int nu8 = nu_elems >> 3;
    for (; i < n8; i += stride) {
        const float4* src = (i < nu8) ? (const float4*)(ue) + 2 * i
                                      : (const float4*)(ie) + 2 * (i - nu8);
        float4 lo = src[0];
        float4 hi = src[1];
        h8v o;
        o[0] = (_Float16)lo.x; o[1] = (_Float16)lo.y;
        o[2] = (_Float16)lo.z; o[3] = (_Float16)lo.w;
        o[4] = (_Float16)hi.x; o[5] = (_Float16)hi.y;
        o[6] = (_Float16)hi.z; o[7] = (_Float16)hi.w;
        reinterpret_cast<h8v*>(xh)[i] = o;
    }
}

// ---------- pass A1: per-block bucket histogram (LDS), bucket-major dump ----------
__global__ __launch_bounds__(256) void bucket_count_kernel(
    const int* __restrict__ rows, int* __restrict__ blockCounts,
    int nnz, int nbuck, int chunk) {
    __shared__ int hist[MAX_NBUCK];
    int t = threadIdx.x, blk = blockIdx.x;
    for (int i = t; i < nbuck; i += 256) hist[i] = 0;
    __syncthreads();
    int e0 = blk * chunk;
    int e1 = min(e0 + chunk, nnz);
    for (int e = e0 + t * 4; e < e1; e += 1024) {
        ix4 r4 = __builtin_nontemporal_load(reinterpret_cast<const ix4*>(rows + e));
        atomicAdd(&hist[r4.x >> BUCKET_SHIFT], 1);
        atomicAdd(&hist[r4.y >> BUCKET_SHIFT], 1);
        atomicAdd(&hist[r4.z >> BUCKET_SHIFT], 1);
        atomicAdd(&hist[r4.w >> BUCKET_SHIFT], 1);
    }
    __syncthreads();
    for (int u = t; u < nbuck; u += 256)
        blockCounts[u * NBLK_A + blk] = hist[u];
}

// ---------- scan phase 1 (chunk 2048): per-block sums ----------
__global__ void scan8_phase1(const int* __restrict__ in, int* __restrict__ bsum, int n) {
    __shared__ int wsum[4];
    int t = threadIdx.x, b = blockIdx.x;
    int i0 = b * SCAN2_CHUNK + t * 8;
    int s = 0;
    #pragma unroll
    for (int k = 0; k < 8; ++k) { int i = i0 + k; if (i < n) s += in[i]; }
    #pragma unroll
    for (int off = 1; off < 64; off <<= 1) s += __shfl_xor(s, off);
    if ((t & 63) == 0) wsum[t >> 6] = s;
    __syncthreads();
    if (t == 0) bsum[b] = wsum[0] + wsum[1] + wsum[2] + wsum[3];
}

// ---------- scan phase 2: single-block scan of block sums (nb <= 512) ----------
__global__ void scan_phase2(const int* __restrict__ bsum, int* __restrict__ boff, int nb) {
    __shared__ int lds[512];
    int t = threadIdx.x;
    lds[t] = (t < nb) ? bsum[t] : 0;
    __syncthreads();
    for (int off = 1; off < 512; off <<= 1) {
        int v = (t >= off) ? lds[t - off] : 0;
        __syncthreads();
        lds[t] += v;
        __syncthreads();
    }
    if (t < nb) boff[t] = (t == 0) ? 0 : lds[t - 1];
}

// ---------- scan phase 3 (chunk 2048): write exclusive prefix ----------
__global__ void scan8_phase3(const int* __restrict__ in, const int* __restrict__ boff,
                             int* __restrict__ out, int n) {
    __shared__ int wexcl[4];
    int t = threadIdx.x, b = blockIdx.x;
    int lane = t & 63, w = t >> 6;
    int i0 = b * SCAN2_CHUNK + t * 8;
    int c[8];
    int s = 0;
    #pragma unroll
    for (int k = 0; k < 8; ++k) { int i = i0 + k; c[k] = (i < n) ? in[i] : 0; s += c[k]; }
    int incl = s;
    #pragma unroll
    for (int off = 1; off < 64; off <<= 1) {
        int u = __shfl_up(incl, off);
        if (lane >= off) incl += u;
    }
    if (lane == 63) wexcl[w] = incl;
    __syncthreads();
    int wbase = 0;
    for (int ww = 0; ww < w; ++ww) wbase += wexcl[ww];
    int run = incl - s + wbase + boff[b];
    #pragma unroll
    for (int k = 0; k < 8; ++k) {
        int i = i0 + k;
        if (i < n) { out[i] = run; run += c[k]; }
    }
}

// ---------- pass A3: scatter edges into bucket-partitioned staging (LDS cursors) ----------
__global__ __launch_bounds__(256) void bucket_scatter_kernel(
    const int* __restrict__ rows, const int* __restrict__ cols,
    const float* __restrict__ vals, const int* __restrict__ scanOut,
    int2* __restrict__ smeta, int nnz, int nbuck, int chunk) {
    __shared__ int cur[MAX_NBUCK];
    int t = threadIdx.x, blk = blockIdx.x;
    for (int u = t; u < nbuck; u += 256) cur[u] = scanOut[u * NBLK_A + blk];
    __syncthreads();
    int e0 = blk * chunk;
    int e1 = min(e0 + chunk, nnz);
    for (int e = e0 + t * 4; e < e1; e += 1024) {
        ix4 r4 = __builtin_nontemporal_load(reinterpret_cast<const ix4*>(rows + e));
        ix4 c4 = __builtin_nontemporal_load(reinterpret_cast<const ix4*>(cols + e));
        fv4 v4 = __builtin_nontemporal_load(reinterpret_cast<const fv4*>(vals + e));
        int p0 = atomicAdd(&cur[r4.x >> BUCKET_SHIFT], 1);
        smeta[p0] = make_int2(((r4.x & (BUCKET_ROWS - 1)) << COL_BITS) | c4.x, __float_as_int(v4.x));
        int p1 = atomicAdd(&cur[r4.y >> BUCKET_SHIFT], 1);
        smeta[p1] = make_int2(((r4.y & (BUCKET_ROWS - 1)) << COL_BITS) | c4.y, __float_as_int(v4.y));
        int p2 = atomicAdd(&cur[r4.z >> BUCKET_SHIFT], 1);
        smeta[p2] = make_int2(((r4.z & (BUCKET_ROWS - 1)) << COL_BITS) | c4.z, __float_as_int(v4.z));
        int p3 = atomicAdd(&cur[r4.w >> BUCKET_SHIFT], 1);
        smeta[p3] = make_int2(((r4.w & (BUCKET_ROWS - 1)) << COL_BITS) | c4.w, __float_as_int(v4.w));
    }
}

// ---------- pass B: per-bucket counting sort -> row_ptr + perm ----------
// Single global read: bucket's smeta staged raw in LDS (histogram during load),
// then placed into perm from LDS. Fallback to double-read if bucket overflows.
__global__ __launch_bounds__(256) void bucket_build_kernel(
    const int2* __restrict__ smeta, const int* __restrict__ scanOut,
    int2* __restrict__ perm, int* __restrict__ row_ptr,
    int nnz, int n_nodes, int nbuck) {
    __shared__ int hist[BUCKET_ROWS], excl[BUCKET_ROWS], cur[BUCKET_ROWS];
    __shared__ int wex[4];
    __shared__ int2 stage[STAGE_CAP];
    int t = threadIdx.x, b = blockIdx.x;
    int lane = t & 63, w = t >> 6;
    int ebeg = scanOut[b * NBLK_A];
    int eend = (b + 1 < nbuck) ? scanOut[(b + 1) * NBLK_A] : nnz;
    int nbe = eend - ebeg;
    hist[t] = 0; hist[t + 256] = 0;
    __syncthreads();
    bool fit = (nbe <= STAGE_CAP);
    if (fit) {
        for (int i = t; i < nbe; i += 256) {
            int2 m = smeta[ebeg + i];
            stage[i] = m;
            atomicAdd(&hist[m.x >> COL_BITS], 1);
        }
    } else {
        for (int e = ebeg + t; e < eend; e += 256)
            atomicAdd(&hist[smeta[e].x >> COL_BITS], 1);
    }
    __syncthreads();
    // 512-bin exclusive scan with 256 threads (2 bins each)
    int a = hist[2 * t], bcnt = hist[2 * t + 1];
    int s = a + bcnt;
    int incl = s;
    #pragma unroll
    for (int off = 1; off < 64; off <<= 1) {
        int u = __shfl_up(incl, off);
        if (lane >= off) incl += u;
    }
    if (lane == 63) wex[w] = incl;
    __syncthreads();
    int wbase = 0;
    for (int ww = 0; ww < w; ++ww) wbase += wex[ww];
    int es = wbase + incl - s;
    excl[2 * t] = es;
    excl[2 * t + 1] = es + a;
    cur[2 * t] = es;
    cur[2 * t + 1] = es + a;
    __syncthreads();
    // write row_ptr for this bucket's rows
    int base_row = b << BUCKET_SHIFT;
    for (int r = t; r < BUCKET_ROWS; r += 256) {
        int gr = base_row + r;
        if (gr < n_nodes) row_ptr[gr] = ebeg + excl[r];
    }
    if (b == 0 && t == 0) row_ptr[n_nodes] = nnz;
    if (fit) {
        for (int i = t; i < nbe; i += 256) {
            int2 m = stage[i];
            int l = m.x >> COL_BITS;
            int p = atomicAdd(&cur[l], 1);
            perm[ebeg + p] = make_int2(m.x & ((1 << COL_BITS) - 1), m.y);
        }
    } else {
        for (int e = ebeg + t; e < eend; e += 256) {
            int2 m = smeta[e];
            int l = m.x >> COL_BITS;
            int p = atomicAdd(&cur[l], 1);
            perm[ebeg + p] = make_int2(m.x & ((1 << COL_BITS) - 1), m.y);
        }
    }
}

// ---------- fp16 CSR gather SpMM: one wave per row, 8 edge-slots x 8 dim-lanes ----------
// 24 edges per iteration (3 independent groups). Packed fp16 partial product
// (<=3 terms) flushed to fp32 per iteration.
__global__ __launch_bounds__(256) void spmm_csr_h_kernel(
    const int* __restrict__ row_ptr, const int2* __restrict__ perm,
    const _Float16* __restrict__ x, _Float16* __restrict__ y, int n_nodes) {
    int lane = threadIdx.x & 63;
    int row = (blockIdx.x * blockDim.x + threadIdx.x) >> 6;
    if (row >= n_nodes) return;
    int start = row_ptr[row];
    int end   = row_ptr[row + 1];
    int sub  = lane >> 3;    // edge slot 0..7
    unsigned dimb = ((unsigned)(lane & 7)) << 4;   // byte offset of half8 within row
    const char* xb = reinterpret_cast<const char*>(x);
    float accf[8];
    #pragma unroll
    for (int k = 0; k < 8; ++k) accf[k] = 0.f;
    for (int base = start; base < end; base += 24) {
        int e0 = base + sub;
        int e1 = e0 + 8;
        int e2 = e0 + 16;
        int2 p0 = (e0 < end) ? perm[e0] : make_int2(0, 0);
        int2 p1 = (e1 < end) ? perm[e1] : make_int2(0, 0);
        int2 p2 = (e2 < end) ? perm[e2] : make_int2(0, 0);
        _Float16 vh0 = (_Float16)__int_as_float(p0.y);
        _Float16 vh1 = (_Float16)__int_as_float(p1.y);
        _Float16 vh2 = (_Float16)__int_as_float(p2.y);
        h8v xv0 = *reinterpret_cast<const h8v*>(xb + ((((unsigned)p0.x) << 7) | dimb));
        h8v xv1 = *reinterpret_cast<const h8v*>(xb + ((((unsigned)p1.x) << 7) | dimb));
        h8v xv2 = *reinterpret_cast<const h8v*>(xb + ((((unsigned)p2.x) << 7) | dimb));
        h8v p = xv0 * vh0;           // packed fp16 math
        p += xv1 * vh1;
        p += xv2 * vh2;
        #pragma unroll
        for (int k = 0; k < 8; ++k) accf[k] += (float)p[k];
    }
    #pragma unroll
    for (int off = 8; off < 64; off <<= 1) {
        #pragma unroll
        for (int k = 0; k < 8; ++k) accf[k] += __shfl_xor(accf[k], off);
    }
    if (sub == 0) {
        h8v o;
        #pragma unroll
        for (int k = 0; k < 8; ++k) o[k] = (_Float16)accf[k];
        *reinterpret_cast<h8v*>(reinterpret_cast<char*>(y) + ((((unsigned)row) << 7) | dimb)) = o;
    }
}

// ---------- fused layer-3 batch SpMM + full accumulation + scoring ----------
// One wave per batch element: gather layer-3 sums for its u-row and i-row from
// x2 (= bufB), add layer-0/1/2 terms read directly from xh/bufA/bufB rows, dot,
// write out[b]. No separate batch accumulators needed.
__global__ __launch_bounds__(256) void spmm_batch_score_kernel(
    const int* __restrict__ row_ptr, const int2* __restrict__ perm,
    const _Float16* __restrict__ x0,   // layer-0 (xh)
    const _Float16* __restrict__ x1,   // layer-1 (bufA)
    const _Float16* __restrict__ x2,   // layer-2 (bufB), also the l3 gather source
    const int* __restrict__ uids, const int* __restrict__ iids,
    float* __restrict__ out, int batch, int num_users) {
    int lane = threadIdx.x & 63;
    int b = (blockIdx.x * blockDim.x + threadIdx.x) >> 6;
    if (b >= batch) return;
    int sub  = lane >> 3;
    int dimq = lane & 7;
    unsigned dimb = ((unsigned)dimq) << 4;
    const char* xb = reinterpret_cast<const char*>(x2);
    int urow = uids[b];
    int irow = num_users + iids[b];
    float u3[8], i3[8];
    #pragma unroll
    for (int k = 0; k < 8; ++k) { u3[k] = 0.f; i3[k] = 0.f; }
    // --- u row layer-3 ---
    {
        int start = row_ptr[urow];
        int end   = row_ptr[urow + 1];
        for (int base = start; base < end; base += 16) {
            int e0 = base + sub;
            int e1 = e0 + 8;
            int2 p0 = (e0 < end) ? perm[e0] : make_int2(0, 0);
            int2 p1 = (e1 < end) ? perm[e1] : make_int2(0, 0);
            _Float16 vh0 = (_Float16)__int_as_float(p0.y);
            _Float16 vh1 = (_Float16)__int_as_float(p1.y);
            h8v xv0 = *reinterpret_cast<const h8v*>(xb + ((((unsigned)p0.x) << 7) | dimb));
            h8v xv1 = *reinterpret_cast<const h8v*>(xb + ((((unsigned)p1.x) << 7) | dimb));
            h8v p = xv0 * vh0;
            p += xv1 * vh1;
            #pragma unroll
            for (int k = 0; k < 8; ++k) u3[k] += (float)p[k];
        }
    }
    // --- i row layer-3 ---
    {
        int start = row_ptr[irow];
        int end   = row_ptr[irow + 1];
        for (int base = start; base < end; base += 16) {
            int e0 = base + sub;
            int e1 = e0 + 8;
            int2 p0 = (e0 < end) ? perm[e0] : make_int2(0, 0);
            int2 p1 = (e1 < end) ? perm[e1] : make_int2(0, 0);
            _Float16 vh0 = (_Float16)__int_as_float(p0.y);
            _Float16 vh1 = (_Float16)__int_as_float(p1.y);
            h8v xv0 = *reinterpret_cast<const h8v*>(xb + ((((unsigned)p0.x) << 7) | dimb));
            h8v xv1 = *reinterpret_cast<const h8v*>(xb + ((((unsigned)p1.x) << 7) | dimb));
            h8v p = xv0 * vh0;
            p += xv1 * vh1;
            #pragma unroll
            for (int k = 0; k < 8; ++k) i3[k] += (float)p[k];
        }
    }
    #pragma unroll
    for (int off = 8; off < 64; off <<= 1) {
        #pragma unroll
        for (int k = 0; k < 8; ++k) {
            u3[k] += __shfl_xor(u3[k], off);
            i3[k] += __shfl_xor(i3[k], off);
        }
    }
    // layer-0/1/2 terms, read directly from the node buffers (coalesced broadcasts)
    unsigned uoff = (((unsigned)urow) << 7) | dimb;
    unsigned ioff = (((unsigned)irow) << 7) | dimb;
    h8v u0 = *reinterpret_cast<const h8v*>(reinterpret_cast<const char*>(x0) + uoff);
    h8v u1 = *reinterpret_cast<const h8v*>(reinterpret_cast<const char*>(x1) + uoff);
    h8v u2 = *reinterpret_cast<const h8v*>(reinterpret_cast<const char*>(x2) + uoff);
    h8v i0 = *reinterpret_cast<const h8v*>(reinterpret_cast<const char*>(x0) + ioff);
    h8v i1 = *reinterpret_cast<const h8v*>(reinterpret_cast<const char*>(x1) + ioff);
    h8v i2 = *reinterpret_cast<const h8v*>(reinterpret_cast<const char*>(x2) + ioff);
    float s = 0.f;
    #pragma unroll
    for (int k = 0; k < 8; ++k) {
        float su = (float)u0[k] + (float)u1[k] + (float)u2[k] + u3[k];
        float si = (float)i0[k] + (float)i1[k] + (float)i2[k] + i3[k];
        s += su * si;
    }
    #pragma unroll
    for (int off = 1; off < 8; off <<= 1) s += __shfl_xor(s, off);
    if (lane == 0) out[b] = s * (1.0f / 16.0f);  // (acc/4)·(acc/4)
}

extern "C" void kernel_launch(void* const* d_in, const int* in_sizes, int n_in,
                              void* d_out, int out_size, void* d_ws, size_t ws_size,
                              hipStream_t stream) {
    const float* user_emb = (const float*)d_in[0];
    const float* item_emb = (const float*)d_in[1];
    const int*   adj_rows = (const int*)d_in[2];
    const int*   adj_cols = (const int*)d_in[3];
    const float* adj_vals = (const float*)d_in[4];
    const int*   user_ids = (const int*)d_in[5];
    const int*   item_ids = (const int*)d_in[6];
    float* out = (float*)d_out;

    const int num_users = in_sizes[0] / EMBED_DIM;   // 200000
    const int num_items = in_sizes[1] / EMBED_DIM;   // 100000
    const int n_nodes   = num_users + num_items;     // 300000
    const int nnz       = in_sizes[2];               // 6000000
    const int batch     = in_sizes[5];               // 16384

    const long node_elems = (long)n_nodes * EMBED_DIM;    // 19.2M elems

    const int nbuck = (n_nodes + BUCKET_ROWS - 1) >> BUCKET_SHIFT;   // 586
    const int nscan = nbuck * NBLK_A;                                // 150016
    const int nscan_blocks = (nscan + SCAN2_CHUNK - 1) / SCAN2_CHUNK; // 74

    // ---- workspace layout ----
    char* wp = (char*)d_ws;
    _Float16* xh   = (_Float16*)wp;      wp += node_elems * sizeof(_Float16);
    _Float16* bufA = (_Float16*)wp;      wp += node_elems * sizeof(_Float16);
    _Float16* bufB = (_Float16*)wp;      wp += node_elems * sizeof(_Float16);
    int*   row_ptr = (int*)wp;           wp += (size_t)(n_nodes + 4) * sizeof(int);
    int*   bsum    = (int*)wp;           wp += 512 * sizeof(int);
    int*   boff    = (int*)wp;           wp += 512 * sizeof(int);
    int*   blockCounts = (int*)wp;       wp += (size_t)nscan * sizeof(int);
    int*   scanOut     = (int*)wp;       wp += (size_t)nscan * sizeof(int);
    wp = (char*)(((uintptr_t)wp + 15) & ~(uintptr_t)15);
    int2*  perm    = (int2*)wp;          wp += (size_t)nnz * sizeof(int2);

    // smeta staging (48 MB) overlays bufA+bufB (76.8 MB contiguous): both are
    // first written by spmm layers, which run after bucket_build consumes smeta.
    int2* smeta = (int2*)bufA;

    const int chunkA = (((nnz + NBLK_A - 1) / NBLK_A) + 1023) & ~1023;   // 24576

    // ---- radix CSR build (no device atomics) ----
    bucket_count_kernel<<<NBLK_A, 256, 0, stream>>>(adj_rows, blockCounts, nnz, nbuck, chunkA);
    scan8_phase1<<<nscan_blocks, 256, 0, stream>>>(blockCounts, bsum, nscan);
    scan_phase2<<<1, 512, 0, stream>>>(bsum, boff, nscan_blocks);
    scan8_phase3<<<nscan_blocks, 256, 0, stream>>>(blockCounts, boff, scanOut, nscan);
    bucket_scatter_kernel<<<NBLK_A, 256, 0, stream>>>(adj_rows, adj_cols, adj_vals,
                                                      scanOut, smeta, nnz, nbuck, chunkA);
    bucket_build_kernel<<<nbuck, 256, 0, stream>>>(smeta, scanOut, perm,
                                                   row_ptr, nnz, n_nodes, nbuck);

    // ---- convert x0 to fp16 ----
    convert_x_kernel<<<2048, 256, 0, stream>>>(user_emb, item_emb, xh,
                                               num_users * EMBED_DIM, (int)node_elems);

    const int spmm_blocks = ((n_nodes * 64) + 255) / 256;   // one wave per row

    // ---- layer 1: xh -> bufA ----
    spmm_csr_h_kernel<<<spmm_blocks, 256, 0, stream>>>(row_ptr, perm, xh, bufA, n_nodes);

    // ---- layer 2: bufA -> bufB ----
    spmm_csr_h_kernel<<<spmm_blocks, 256, 0, stream>>>(row_ptr, perm, bufA, bufB, n_nodes);

    // ---- layer 3 (batch-restricted) fused with accumulation + scoring ----
    {
        int blocks = (batch * 64 + 255) / 256;       // one wave per batch element
        spmm_batch_score_kernel<<<blocks, 256, 0, stream>>>(row_ptr, perm,
                                                            xh, bufA, bufB,
                                                            user_ids, item_ids,
                                                            out, batch, num_users);
    }
}